// Round 2
// baseline (2902.277 us; speedup 1.0000x reference)
//
#include <hip/hip_runtime.h>
#include <hip/hip_bf16.h>

// Problem constants (B,N,M,D,H from reference)
#define BB 4
#define NN 512
#define MM 4096
#define DD 256
#define HH 8
#define HDD 32
static constexpr float SCALE = 0.17677669529663687f; // 1/sqrt(32)

// ---------------------------------------------------------------------------
// Input projection: Y[rows,256] = X[rows,256] @ W[256,256], all f32.
// Block: 256 threads, 16 rows per block. Thread owns one output column c.
// ---------------------------------------------------------------------------
__global__ __launch_bounds__(256) void proj_gemm(
    const float* __restrict__ X,
    const float* __restrict__ W,
    float* __restrict__ Y)
{
    __shared__ float xs[16][DD];
    const int c = threadIdx.x;
    const int r0 = blockIdx.x * 16;
    #pragma unroll
    for (int r = 0; r < 16; ++r)
        xs[r][c] = X[(size_t)(r0 + r) * DD + c];
    __syncthreads();
    float acc[16];
    #pragma unroll
    for (int r = 0; r < 16; ++r) acc[r] = 0.f;
    for (int k = 0; k < DD; ++k) {
        const float w = W[(size_t)k * DD + c];
        #pragma unroll
        for (int r = 0; r < 16; ++r) acc[r] += xs[r][k] * w;
    }
    #pragma unroll
    for (int r = 0; r < 16; ++r)
        Y[(size_t)(r0 + r) * DD + c] = acc[r];
}

// ---------------------------------------------------------------------------
// Output projection + bias + elementwise multiply with original feats.
// out[r,c] = (ctx[r,:] @ W[:,c] + bias[c]) * feats[r,c]
// ---------------------------------------------------------------------------
__global__ __launch_bounds__(256) void outproj_mul(
    const float* __restrict__ ctx,
    const float* __restrict__ W,
    const float* __restrict__ bias,
    const float* __restrict__ feats,
    float* __restrict__ out)
{
    __shared__ float xs[16][DD];
    const int c = threadIdx.x;
    const int r0 = blockIdx.x * 16;
    #pragma unroll
    for (int r = 0; r < 16; ++r)
        xs[r][c] = ctx[(size_t)(r0 + r) * DD + c];
    __syncthreads();
    float acc[16];
    #pragma unroll
    for (int r = 0; r < 16; ++r) acc[r] = 0.f;
    for (int k = 0; k < DD; ++k) {
        const float w = W[(size_t)k * DD + c];
        #pragma unroll
        for (int r = 0; r < 16; ++r) acc[r] += xs[r][k] * w;
    }
    const float bv = bias[c];
    #pragma unroll
    for (int r = 0; r < 16; ++r) {
        const size_t idx = (size_t)(r0 + r) * DD + c;
        out[idx] = (acc[r] + bv) * feats[idx];
    }
}

// ---------------------------------------------------------------------------
// Direction A: amr -> visual. One block per (b,h,n). Softmax over m=4096.
// ---------------------------------------------------------------------------
__global__ __launch_bounds__(256) void attn_amr2vis(
    const float* __restrict__ amr_qk,
    const float* __restrict__ vis_qk,
    const float* __restrict__ vis_v,
    float* __restrict__ ctx0)
{
    const int bid = blockIdx.x;
    const int n = bid % NN;
    const int bh = bid / NN;
    const int h = bh % HH;
    const int b = bh / HH;
    const int tid = threadIdx.x;

    __shared__ float q[HDD];
    __shared__ float sc[MM];      // 16 KB
    __shared__ float red[256];
    __shared__ float part[8][HDD];

    if (tid < HDD) q[tid] = amr_qk[(size_t)(b * NN + n) * DD + h * HDD + tid];
    __syncthreads();

    float lmax = -3.4e38f;
    for (int m = tid; m < MM; m += 256) {
        const float* vq = &vis_qk[(size_t)(b * MM + m) * DD + h * HDD];
        float d = 0.f;
        #pragma unroll
        for (int c = 0; c < HDD; ++c) d += vq[c] * q[c];
        d *= SCALE;
        sc[m] = d;
        lmax = fmaxf(lmax, d);
    }
    red[tid] = lmax;
    __syncthreads();
    for (int s = 128; s > 0; s >>= 1) {
        if (tid < s) red[tid] = fmaxf(red[tid], red[tid + s]);
        __syncthreads();
    }
    const float mx = red[0];
    __syncthreads();

    float lsum = 0.f;
    for (int m = tid; m < MM; m += 256) {
        const float e = expf(sc[m] - mx);
        sc[m] = e;
        lsum += e;
    }
    red[tid] = lsum;
    __syncthreads();
    for (int s = 128; s > 0; s >>= 1) {
        if (tid < s) red[tid] += red[tid + s];
        __syncthreads();
    }
    const float inv = 1.f / red[0];

    // PV: 8 groups of 32 lanes; group g sums m = g, g+8, ...
    const int c = tid & 31;
    const int g = tid >> 5;
    float acc = 0.f;
    for (int m = g; m < MM; m += 8)
        acc += sc[m] * vis_v[(size_t)(b * MM + m) * DD + h * HDD + c];
    part[g][c] = acc;
    __syncthreads();
    if (tid < HDD) {
        float s2 = 0.f;
        #pragma unroll
        for (int gg = 0; gg < 8; ++gg) s2 += part[gg][tid];
        ctx0[(size_t)(b * NN + n) * DD + h * HDD + tid] = s2 * inv;
    }
}

// ---------------------------------------------------------------------------
// Direction B: visual -> amr, masked. One block per (b,h,m). Softmax over n=512.
// ---------------------------------------------------------------------------
__global__ __launch_bounds__(256) void attn_vis2amr(
    const float* __restrict__ vis_qk,
    const float* __restrict__ amr_qk,
    const float* __restrict__ amr_v,
    const int* __restrict__ mask,   // nonzero = masked (pad)
    float* __restrict__ ctx1)
{
    const int bid = blockIdx.x;
    const int m = bid % MM;
    const int bh = bid / MM;
    const int h = bh % HH;
    const int b = bh / HH;
    const int tid = threadIdx.x;

    __shared__ float q[HDD];
    __shared__ float sc[NN];      // 2 KB
    __shared__ float red[256];
    __shared__ float part[8][HDD];

    if (tid < HDD) q[tid] = vis_qk[(size_t)(b * MM + m) * DD + h * HDD + tid];
    __syncthreads();

    float lmax = -3.4e38f;
    for (int n = tid; n < NN; n += 256) {
        float d;
        if (mask[b * NN + n] != 0) {
            d = -3.4e38f;
        } else {
            const float* aq = &amr_qk[(size_t)(b * NN + n) * DD + h * HDD];
            d = 0.f;
            #pragma unroll
            for (int c = 0; c < HDD; ++c) d += aq[c] * q[c];
            d *= SCALE;
        }
        sc[n] = d;
        lmax = fmaxf(lmax, d);
    }
    red[tid] = lmax;
    __syncthreads();
    for (int s = 128; s > 0; s >>= 1) {
        if (tid < s) red[tid] = fmaxf(red[tid], red[tid + s]);
        __syncthreads();
    }
    const float mx = red[0];
    __syncthreads();

    float lsum = 0.f;
    for (int n = tid; n < NN; n += 256) {
        const float e = expf(sc[n] - mx);
        sc[n] = e;
        lsum += e;
    }
    red[tid] = lsum;
    __syncthreads();
    for (int s = 128; s > 0; s >>= 1) {
        if (tid < s) red[tid] += red[tid + s];
        __syncthreads();
    }
    const float inv = 1.f / red[0];

    const int c = tid & 31;
    const int g = tid >> 5;
    float acc = 0.f;
    for (int n = g; n < NN; n += 8)
        acc += sc[n] * amr_v[(size_t)(b * NN + n) * DD + h * HDD + c];
    part[g][c] = acc;
    __syncthreads();
    if (tid < HDD) {
        float s2 = 0.f;
        #pragma unroll
        for (int gg = 0; gg < 8; ++gg) s2 += part[gg][tid];
        ctx1[(size_t)(b * MM + m) * DD + h * HDD + tid] = s2 * inv;
    }
}

// ---------------------------------------------------------------------------
extern "C" void kernel_launch(void* const* d_in, const int* in_sizes, int n_in,
                              void* d_out, int out_size, void* d_ws, size_t ws_size,
                              hipStream_t stream)
{
    const float* amr_feats    = (const float*)d_in[0];
    const int*   amr_pad_mask = (const int*)d_in[1];
    const float* visual_feats = (const float*)d_in[2];
    const float* W_amr_qk     = (const float*)d_in[3];
    const float* W_amr_v      = (const float*)d_in[4];
    const float* W_vis_qk     = (const float*)d_in[5];
    const float* W_vis_v      = (const float*)d_in[6];
    const float* W_amr_out    = (const float*)d_in[7];
    const float* b_amr_out    = (const float*)d_in[8];
    const float* W_vis_out    = (const float*)d_in[9];
    const float* b_vis_out    = (const float*)d_in[10];

    // workspace layout (f32), with ctx1 reusing vis_v (never read together):
    // amr_qk  [0       , 524288 )
    // amr_v   [524288  , 1048576)
    // vis_qk  [1048576 , 5242880)
    // vis_v   [5242880 , 9437184)   <- reused as ctx1 after attn_amr2vis
    // ctx0    [9437184 , 9961472)
    // total 9,961,472 floats = 39.8 MB
    float* ws      = (float*)d_ws;
    float* amr_qk  = ws;
    float* amr_v   = ws + 524288;
    float* vis_qk  = ws + 1048576;
    float* vis_v   = ws + 5242880;
    float* ctx0    = ws + 9437184;
    float* ctx1    = vis_v;   // alias: attn_vis2amr does not read vis_v

    float* out0 = (float*)d_out;                 // 4*512*256
    float* out1 = out0 + (size_t)BB * NN * DD;   // 4*4096*256

    // 1) input projections
    proj_gemm<<<BB * NN / 16, 256, 0, stream>>>(amr_feats, W_amr_qk, amr_qk);
    proj_gemm<<<BB * NN / 16, 256, 0, stream>>>(amr_feats, W_amr_v, amr_v);
    proj_gemm<<<BB * MM / 16, 256, 0, stream>>>(visual_feats, W_vis_qk, vis_qk);
    proj_gemm<<<BB * MM / 16, 256, 0, stream>>>(visual_feats, W_vis_v, vis_v);

    // 2) attention: dir A first (consumes vis_v), then dir B (writes over it)
    attn_amr2vis<<<BB * HH * NN, 256, 0, stream>>>(amr_qk, vis_qk, vis_v, ctx0);
    attn_vis2amr<<<BB * HH * MM, 256, 0, stream>>>(vis_qk, amr_qk, amr_v,
                                                   amr_pad_mask, ctx1);

    // 3) output projections + bias + elementwise multiply
    outproj_mul<<<BB * NN / 16, 256, 0, stream>>>(ctx0, W_amr_out, b_amr_out,
                                                  amr_feats, out0);
    outproj_mul<<<BB * MM / 16, 256, 0, stream>>>(ctx1, W_vis_out, b_vis_out,
                                                  visual_feats, out1);
}

// Round 3
// 787.697 us; speedup vs baseline: 3.6845x; 3.6845x over previous
//
#include <hip/hip_runtime.h>

#define BB 4
#define NN 512
#define MM 4096
#define DD 256
#define HH 8
#define HDD 32
static constexpr float SCALE = 0.17677669529663687f; // 1/sqrt(32)

// ---------------------------------------------------------------------------
// Projection kernel: Y[rows,256] = X[rows,256] @ W[256,256]  (f32)
// OUTPROJ adds bias and multiplies by feats elementwise.
// 32 rows per block, 256 threads (thread = output column).
// X tile staged TRANSPOSED in LDS -> inner loop reads broadcast float4.
// ---------------------------------------------------------------------------
template<bool OUTPROJ>
__global__ __launch_bounds__(256) void proj_kernel(
    const float* __restrict__ X,
    const float* __restrict__ W,
    const float* __restrict__ bias,
    const float* __restrict__ feats,
    float* __restrict__ Y)
{
    __shared__ float xst[DD][36];   // [k][r], stride 36 (4-aligned, conflict-light)
    const int c = threadIdx.x;
    const int r0 = blockIdx.x * 32;

    #pragma unroll 8
    for (int r = 0; r < 32; ++r)
        xst[c][r] = X[(size_t)(r0 + r) * DD + c];
    __syncthreads();

    float acc[32];
    #pragma unroll
    for (int r = 0; r < 32; ++r) acc[r] = 0.f;

    for (int k = 0; k < DD; ++k) {
        const float w = W[(size_t)k * DD + c];
        const float4* xrow = (const float4*)&xst[k][0];
        #pragma unroll
        for (int r4 = 0; r4 < 8; ++r4) {
            const float4 x4 = xrow[r4];
            acc[r4 * 4 + 0] += x4.x * w;
            acc[r4 * 4 + 1] += x4.y * w;
            acc[r4 * 4 + 2] += x4.z * w;
            acc[r4 * 4 + 3] += x4.w * w;
        }
    }

    if (OUTPROJ) {
        const float bv = bias[c];
        #pragma unroll 8
        for (int r = 0; r < 32; ++r) {
            const size_t idx = (size_t)(r0 + r) * DD + c;
            Y[idx] = (acc[r] + bv) * feats[idx];
        }
    } else {
        #pragma unroll 8
        for (int r = 0; r < 32; ++r)
            Y[(size_t)(r0 + r) * DD + c] = acc[r];
    }
}

// ---------------------------------------------------------------------------
// Unified flash attention tile kernel (f32).
//   Q:[B,NQ,256]  K,V:[B,SEQK,256]  per head h (offset h*32), ctx:[B,NQ,256]
//   32 queries per block, key tiles of KT=128, online softmax.
//   Optional key mask (dir B: visual->amr masked by amr_pad_mask).
// Thread roles:
//   score phase: mlane = tid&127 (key row, K held in 8xfloat4 regs),
//                qhalf = (tid>>7)*16 -> 16 queries each
//   reduce/exp : qr = tid>>3 (row), jr = tid&7 (8 lanes/row, shfl_xor reduce)
//   PV phase   : cpv = tid&31 (out col), qg = tid>>5 -> queries qg+{0,8,16,24}
// ---------------------------------------------------------------------------
template<int SEQK, bool HAS_MASK>
__global__ __launch_bounds__(256) void attn_flash(
    const float* __restrict__ Qm,
    const float* __restrict__ Km,
    const float* __restrict__ Vm,
    const int* __restrict__ mask,
    float* __restrict__ ctx,
    int NQ)
{
    constexpr int KT = 128;
    constexpr int NTILES = SEQK / KT;

    __shared__ float qs[32][32];          // [q][c]
    __shared__ float vst[32][KT + 4];     // [c][m]  (transposed V tile)
    __shared__ float sc[32][KT + 4];      // [q][m]  scores -> P
    __shared__ float mrun[32], lrun[32], scalef[32];
    __shared__ float maskadd[KT];

    const int tid = threadIdx.x;
    const int nqt = NQ / 32;
    const int qt  = blockIdx.x % nqt;
    const int h   = (blockIdx.x / nqt) % HH;
    const int b   = blockIdx.x / (nqt * HH);
    const int q0  = qt * 32;

    // prologue: Q tile -> LDS (one float4 per thread)
    {
        const int row = tid >> 3, c4 = tid & 7;
        const float4 v = *(const float4*)
            &Qm[((size_t)b * NQ + q0 + row) * DD + h * HDD + c4 * 4];
        *(float4*)&qs[row][c4 * 4] = v;
    }
    if (tid < 32) { mrun[tid] = -1e30f; lrun[tid] = 0.f; }

    const int mlane = tid & 127;
    const int qhalf = (tid >> 7) * 16;
    const int qr = tid >> 3, jr = tid & 7;
    const int cpv = tid & 31, qg = tid >> 5;

    float acc0 = 0.f, acc1 = 0.f, acc2 = 0.f, acc3 = 0.f;

    for (int t = 0; t < NTILES; ++t) {
        const int m0 = t * KT;

        // (a) K row for this lane -> 32 regs (global, L2-hot)
        float4 k4[8];
        {
            const float* kr = &Km[((size_t)b * SEQK + m0 + mlane) * DD + h * HDD];
            #pragma unroll
            for (int j = 0; j < 8; ++j) k4[j] = *(const float4*)&kr[4 * j];
        }

        __syncthreads();   // previous PV done with vst/sc

        // (b) stage V tile transposed (+ mask adds)
        #pragma unroll
        for (int i = 0; i < 4; ++i) {
            const int f = tid + i * 256;
            const int m = f >> 3, c4 = f & 7;
            const float4 v = *(const float4*)
                &Vm[((size_t)b * SEQK + m0 + m) * DD + h * HDD + c4 * 4];
            vst[c4 * 4 + 0][m] = v.x;
            vst[c4 * 4 + 1][m] = v.y;
            vst[c4 * 4 + 2][m] = v.z;
            vst[c4 * 4 + 3][m] = v.w;
        }
        if (HAS_MASK && tid < KT)
            maskadd[tid] = mask[b * SEQK + m0 + tid] ? -1e30f : 0.f;

        __syncthreads();

        // (c) scores: 16 queries x 1 key per thread
        {
            const float madd = HAS_MASK ? maskadd[mlane] : 0.f;
            #pragma unroll
            for (int qq = 0; qq < 16; ++qq) {
                const int q = qhalf + qq;
                const float4* qrow = (const float4*)&qs[q][0];
                float d = 0.f;
                #pragma unroll
                for (int j = 0; j < 8; ++j) {
                    const float4 a = qrow[j];
                    d += a.x * k4[j].x + a.y * k4[j].y
                       + a.z * k4[j].z + a.w * k4[j].w;
                }
                sc[q][mlane] = d * SCALE + madd;
            }
        }
        __syncthreads();

        // (d) row max + online rescale factors
        {
            float lm = -3.4e38f;
            #pragma unroll
            for (int k = 0; k < 16; ++k)
                lm = fmaxf(lm, sc[qr][jr * 16 + k]);
            lm = fmaxf(lm, __shfl_xor(lm, 1));
            lm = fmaxf(lm, __shfl_xor(lm, 2));
            lm = fmaxf(lm, __shfl_xor(lm, 4));
            const float mold = mrun[qr];
            const float mnew = fmaxf(mold, lm);
            if (jr == 0) {
                const float sf = __expf(mold - mnew);
                mrun[qr] = mnew;
                scalef[qr] = sf;
                lrun[qr] *= sf;
            }
        }
        __syncthreads();

        // (e) P = exp(s - m), row sums
        {
            const float mnew = mrun[qr];
            float s = 0.f;
            #pragma unroll
            for (int k = 0; k < 16; ++k) {
                const float p = __expf(sc[qr][jr * 16 + k] - mnew);
                sc[qr][jr * 16 + k] = p;
                s += p;
            }
            s += __shfl_xor(s, 1);
            s += __shfl_xor(s, 2);
            s += __shfl_xor(s, 4);
            if (jr == 0) lrun[qr] += s;
        }
        __syncthreads();

        // (f) PV accumulate (4 queries per thread)
        {
            acc0 *= scalef[qg];
            acc1 *= scalef[qg + 8];
            acc2 *= scalef[qg + 16];
            acc3 *= scalef[qg + 24];
            #pragma unroll
            for (int m4 = 0; m4 < KT / 4; ++m4) {
                const float4 v  = *(const float4*)&vst[cpv    ][m4 * 4];
                const float4 p0 = *(const float4*)&sc[qg      ][m4 * 4];
                const float4 p1 = *(const float4*)&sc[qg +  8 ][m4 * 4];
                const float4 p2 = *(const float4*)&sc[qg + 16 ][m4 * 4];
                const float4 p3 = *(const float4*)&sc[qg + 24 ][m4 * 4];
                acc0 += p0.x * v.x + p0.y * v.y + p0.z * v.z + p0.w * v.w;
                acc1 += p1.x * v.x + p1.y * v.y + p1.z * v.z + p1.w * v.w;
                acc2 += p2.x * v.x + p2.y * v.y + p2.z * v.z + p2.w * v.w;
                acc3 += p3.x * v.x + p3.y * v.y + p3.z * v.z + p3.w * v.w;
            }
        }
    }

    // epilogue: normalize and write (lanes cpv consecutive -> coalesced)
    const size_t base = ((size_t)b * NQ + q0) * DD + h * HDD + cpv;
    ctx[base + (size_t)(qg     ) * DD] = acc0 / lrun[qg];
    ctx[base + (size_t)(qg +  8) * DD] = acc1 / lrun[qg + 8];
    ctx[base + (size_t)(qg + 16) * DD] = acc2 / lrun[qg + 16];
    ctx[base + (size_t)(qg + 24) * DD] = acc3 / lrun[qg + 24];
}

// ---------------------------------------------------------------------------
extern "C" void kernel_launch(void* const* d_in, const int* in_sizes, int n_in,
                              void* d_out, int out_size, void* d_ws, size_t ws_size,
                              hipStream_t stream)
{
    const float* amr_feats    = (const float*)d_in[0];
    const int*   amr_pad_mask = (const int*)d_in[1];
    const float* visual_feats = (const float*)d_in[2];
    const float* W_amr_qk     = (const float*)d_in[3];
    const float* W_amr_v      = (const float*)d_in[4];
    const float* W_vis_qk     = (const float*)d_in[5];
    const float* W_vis_v      = (const float*)d_in[6];
    const float* W_amr_out    = (const float*)d_in[7];
    const float* b_amr_out    = (const float*)d_in[8];
    const float* W_vis_out    = (const float*)d_in[9];
    const float* b_vis_out    = (const float*)d_in[10];

    // workspace layout (f32); ctx1 aliases vis_v (dir B never reads vis_v,
    // and dir A completed before dir B on the same stream)
    float* ws      = (float*)d_ws;
    float* amr_qk  = ws;                  // 2048*256
    float* amr_v   = ws + 524288;         // 2048*256
    float* vis_qk  = ws + 1048576;        // 16384*256
    float* vis_v   = ws + 5242880;        // 16384*256
    float* ctx0    = ws + 9437184;        // 2048*256
    float* ctx1    = vis_v;

    float* out0 = (float*)d_out;                 // 4*512*256
    float* out1 = out0 + (size_t)BB * NN * DD;   // 4*4096*256

    // 1) input projections
    proj_kernel<false><<<BB * NN / 32, 256, 0, stream>>>(
        amr_feats, W_amr_qk, nullptr, nullptr, amr_qk);
    proj_kernel<false><<<BB * NN / 32, 256, 0, stream>>>(
        amr_feats, W_amr_v, nullptr, nullptr, amr_v);
    proj_kernel<false><<<BB * MM / 32, 256, 0, stream>>>(
        visual_feats, W_vis_qk, nullptr, nullptr, vis_qk);
    proj_kernel<false><<<BB * MM / 32, 256, 0, stream>>>(
        visual_feats, W_vis_v, nullptr, nullptr, vis_v);

    // 2) attention
    //    dir A: Q=amr (512), K/V=vis (4096), no mask
    attn_flash<MM, false><<<BB * HH * (NN / 32), 256, 0, stream>>>(
        amr_qk, vis_qk, vis_v, nullptr, ctx0, NN);
    //    dir B: Q=vis (4096), K/V=amr (512), key mask = amr_pad_mask
    attn_flash<NN, true><<<BB * HH * (MM / 32), 256, 0, stream>>>(
        vis_qk, amr_qk, amr_v, amr_pad_mask, ctx1, MM);

    // 3) output projections + bias + elementwise multiply
    proj_kernel<true><<<BB * NN / 32, 256, 0, stream>>>(
        ctx0, W_amr_out, b_amr_out, amr_feats, out0);
    proj_kernel<true><<<BB * MM / 32, 256, 0, stream>>>(
        ctx1, W_vis_out, b_vis_out, visual_feats, out1);
}

// Round 4
// 222.030 us; speedup vs baseline: 13.0715x; 3.5477x over previous
//
#include <hip/hip_runtime.h>

#define BB 4
#define NN 512
#define MM 4096
#define DD 256
#define HH 8
#define HDD 32

typedef __attribute__((ext_vector_type(8))) short bf16x8;
typedef __attribute__((ext_vector_type(4))) float f32x4;

__device__ __forceinline__ unsigned short f2b(float f) {
    union { float f; unsigned u; } v; v.f = f;
    unsigned r = v.u + 0x7fffu + ((v.u >> 16) & 1u);
    return (unsigned short)(r >> 16);
}

// ---------------------------------------------------------------------------
// f32 -> bf16 flat conversion (vectorized, exact-grid)
// ---------------------------------------------------------------------------
__global__ __launch_bounds__(256) void convert_flat(
    const float* __restrict__ src, unsigned short* __restrict__ dst)
{
    const int i = blockIdx.x * 256 + threadIdx.x;
    const float4 v = ((const float4*)src)[i];
    ushort4 o;
    o.x = f2b(v.x); o.y = f2b(v.y); o.z = f2b(v.z); o.w = f2b(v.w);
    ((ushort4*)dst)[i] = o;
}

// ---------------------------------------------------------------------------
// Convert + transpose the 6 weight matrices: Wt[c][k] = bf16(W[k][c])
// grid = 6*256 blocks, 256 threads. Tiny (65k el each).
// ---------------------------------------------------------------------------
struct WPack { const float* s[6]; unsigned short* d[6]; };
__global__ __launch_bounds__(256) void convert_w(WPack p)
{
    const int mat = blockIdx.x >> 8;
    const int k = blockIdx.x & 255;
    const int c = threadIdx.x;
    p.d[mat][(size_t)c * DD + k] = f2b(p.s[mat][(size_t)k * DD + c]);
}

// ---------------------------------------------------------------------------
// bf16 MFMA GEMM: C[R,256] = A[R,256] @ W[256,256]   (Wt[c][k] pre-transposed)
// 64x64 tile, 4 waves (each a 32x32 quadrant), BK=64, K=256.
// OUTPROJ=false: C = bf16( acc * outscale )
// OUTPROJ=true : Cf = (acc + bias[col]) * feats[idx]   (f32 out)
// ---------------------------------------------------------------------------
template<bool OUTPROJ>
__global__ __launch_bounds__(256) void gemm_bf16(
    const unsigned short* __restrict__ A,
    const unsigned short* __restrict__ Wt,
    float outscale,
    const float* __restrict__ bias,
    const float* __restrict__ feats,
    unsigned short* __restrict__ Cb,
    float* __restrict__ Cf)
{
    __shared__ unsigned short As[64][72];   // pitch 144B: 2-way max on frag reads
    __shared__ unsigned short Ws[64][72];
    const int tid = threadIdx.x;
    const int lane = tid & 63, w = tid >> 6;
    const int r0 = blockIdx.x * 64, c0 = blockIdx.y * 64;
    const int rq = (w >> 1) * 32, cq = (w & 1) * 32;
    const int srow = tid >> 2, skc = (tid & 3) * 16;
    const int g = lane >> 4, cl = lane & 15;

    f32x4 acc[2][2] = {};

    for (int ks = 0; ks < DD; ks += 64) {
        __syncthreads();
        {
            const unsigned short* ga = &A[(size_t)(r0 + srow) * DD + ks + skc];
            *(bf16x8*)&As[srow][skc]     = *(const bf16x8*)ga;
            *(bf16x8*)&As[srow][skc + 8] = *(const bf16x8*)(ga + 8);
            const unsigned short* gw = &Wt[(size_t)(c0 + srow) * DD + ks + skc];
            *(bf16x8*)&Ws[srow][skc]     = *(const bf16x8*)gw;
            *(bf16x8*)&Ws[srow][skc + 8] = *(const bf16x8*)(gw + 8);
        }
        __syncthreads();
        #pragma unroll
        for (int kh = 0; kh < 2; ++kh) {
            const int kk = kh * 32 + g * 8;
            const bf16x8 a0 = *(const bf16x8*)&As[rq + cl][kk];
            const bf16x8 a1 = *(const bf16x8*)&As[rq + 16 + cl][kk];
            const bf16x8 b0 = *(const bf16x8*)&Ws[cq + cl][kk];
            const bf16x8 b1 = *(const bf16x8*)&Ws[cq + 16 + cl][kk];
            acc[0][0] = __builtin_amdgcn_mfma_f32_16x16x32_bf16(a0, b0, acc[0][0], 0, 0, 0);
            acc[0][1] = __builtin_amdgcn_mfma_f32_16x16x32_bf16(a0, b1, acc[0][1], 0, 0, 0);
            acc[1][0] = __builtin_amdgcn_mfma_f32_16x16x32_bf16(a1, b0, acc[1][0], 0, 0, 0);
            acc[1][1] = __builtin_amdgcn_mfma_f32_16x16x32_bf16(a1, b1, acc[1][1], 0, 0, 0);
        }
    }

    const int rl = g * 4;
    #pragma unroll
    for (int sr = 0; sr < 2; ++sr)
    #pragma unroll
    for (int sc = 0; sc < 2; ++sc) {
        const int col = c0 + cq + sc * 16 + cl;
        #pragma unroll
        for (int reg = 0; reg < 4; ++reg) {
            const int row = r0 + rq + sr * 16 + rl + reg;
            const size_t idx = (size_t)row * DD + col;
            if (OUTPROJ) {
                Cf[idx] = (acc[sr][sc][reg] + bias[col]) * feats[idx];
            } else {
                Cb[idx] = f2b(acc[sr][sc][reg] * outscale);
            }
        }
    }
}

// ---------------------------------------------------------------------------
// MFMA flash attention. 4 waves x 16 queries = 64 q/block; KV tiles of 64.
// Q/K/V bf16 (scores pre-scaled via sqrt(scale) folded into both qk projs).
// Per-wave in-register online softmax; P transposed via wave-private LDS.
// ---------------------------------------------------------------------------
template<int SEQK, bool HAS_MASK>
__global__ __launch_bounds__(256) void attn_mfma(
    const unsigned short* __restrict__ Qb,
    const unsigned short* __restrict__ Kb,
    const unsigned short* __restrict__ Vb,
    const int* __restrict__ mask,
    unsigned short* __restrict__ ctx,
    int NQ)
{
    __shared__ unsigned short Ks[64][40];      // [key][c]   pitch 80B
    __shared__ unsigned short Vt[32][72];      // [c][m]     pitch 144B
    __shared__ unsigned short Pw[4][16][72];   // per-wave P [q][m]
    __shared__ float maskadd[64];

    const int tid = threadIdx.x;
    const int lane = tid & 63, w = tid >> 6;
    const int nqt = NQ / 64;
    const int qt = blockIdx.x % nqt;
    const int h = (blockIdx.x / nqt) % HH;
    const int b = blockIdx.x / (nqt * HH);
    const int q0 = qt * 64 + w * 16;
    const int g = lane >> 4, c = lane & 15;

    // Q A-fragment, held for the whole kernel
    const bf16x8 aq = *(const bf16x8*)
        &Qb[((size_t)b * NQ + q0 + c) * DD + h * HDD + g * 8];

    float mrun[4], lrun[4];
    #pragma unroll
    for (int r = 0; r < 4; ++r) { mrun[r] = -1e30f; lrun[r] = 0.f; }
    f32x4 acc[2] = {};

    const int kr = tid >> 2, kc = (tid & 3) * 8;   // K staging map
    const int vm = tid & 63, vc = (tid >> 6) * 8;  // V staging map (2-way free)

    for (int t = 0; t < SEQK / 64; ++t) {
        const int m0 = t * 64;
        __syncthreads();
        // stage K tile [64][32]
        *(bf16x8*)&Ks[kr][kc] = *(const bf16x8*)
            &Kb[((size_t)b * SEQK + m0 + kr) * DD + h * HDD + kc];
        // stage V tile transposed: Vt[c][m]
        {
            const bf16x8 v = *(const bf16x8*)
                &Vb[((size_t)b * SEQK + m0 + vm) * DD + h * HDD + vc];
            #pragma unroll
            for (int j = 0; j < 8; ++j)
                Vt[vc + j][vm] = (unsigned short)v[j];
        }
        if (HAS_MASK && tid < 64)
            maskadd[tid] = mask[b * SEQK + m0 + tid] ? -1e30f : 0.f;
        __syncthreads();

        // QK^T: S[16q][64key] in 4 D-frags
        f32x4 s[4];
        #pragma unroll
        for (int kf = 0; kf < 4; ++kf) {
            const bf16x8 bk = *(const bf16x8*)&Ks[kf * 16 + c][g * 8];
            const f32x4 z = {0.f, 0.f, 0.f, 0.f};
            s[kf] = __builtin_amdgcn_mfma_f32_16x16x32_bf16(aq, bk, z, 0, 0, 0);
        }

        // mask + tile row-max
        float lm[4] = {-1e30f, -1e30f, -1e30f, -1e30f};
        #pragma unroll
        for (int kf = 0; kf < 4; ++kf) {
            const float madd = HAS_MASK ? maskadd[kf * 16 + c] : 0.f;
            #pragma unroll
            for (int reg = 0; reg < 4; ++reg) {
                s[kf][reg] += madd;
                lm[reg] = fmaxf(lm[reg], s[kf][reg]);
            }
        }
        #pragma unroll
        for (int reg = 0; reg < 4; ++reg) {
            lm[reg] = fmaxf(lm[reg], __shfl_xor(lm[reg], 1));
            lm[reg] = fmaxf(lm[reg], __shfl_xor(lm[reg], 2));
            lm[reg] = fmaxf(lm[reg], __shfl_xor(lm[reg], 4));
            lm[reg] = fmaxf(lm[reg], __shfl_xor(lm[reg], 8));
        }

        // online-softmax update (all in registers; rows replicated over c-lanes)
        float sf[4], rs[4];
        #pragma unroll
        for (int reg = 0; reg < 4; ++reg) {
            const float mnew = fmaxf(mrun[reg], lm[reg]);
            sf[reg] = __expf(mrun[reg] - mnew);
            mrun[reg] = mnew;
            rs[reg] = 0.f;
        }
        #pragma unroll
        for (int kf = 0; kf < 4; ++kf)
            #pragma unroll
            for (int reg = 0; reg < 4; ++reg) {
                const float p = __expf(s[kf][reg] - mrun[reg]);
                s[kf][reg] = p;
                rs[reg] += p;
            }
        #pragma unroll
        for (int reg = 0; reg < 4; ++reg) {
            rs[reg] += __shfl_xor(rs[reg], 1);
            rs[reg] += __shfl_xor(rs[reg], 2);
            rs[reg] += __shfl_xor(rs[reg], 4);
            rs[reg] += __shfl_xor(rs[reg], 8);
            lrun[reg] = lrun[reg] * sf[reg] + rs[reg];
        }
        #pragma unroll
        for (int sub = 0; sub < 2; ++sub)
            #pragma unroll
            for (int reg = 0; reg < 4; ++reg)
                acc[sub][reg] *= sf[reg];

        // P -> wave-private LDS (bf16), D-layout -> A-layout transpose
        #pragma unroll
        for (int kf = 0; kf < 4; ++kf)
            #pragma unroll
            for (int reg = 0; reg < 4; ++reg)
                Pw[w][g * 4 + reg][kf * 16 + c] = f2b(s[kf][reg]);

        // PV: ctx[16q][32c] += P[16q][64m] x V[64m][32c]
        #pragma unroll
        for (int mh = 0; mh < 2; ++mh) {
            const bf16x8 pa = *(const bf16x8*)&Pw[w][c][mh * 32 + g * 8];
            #pragma unroll
            for (int sub = 0; sub < 2; ++sub) {
                const bf16x8 bv = *(const bf16x8*)&Vt[sub * 16 + c][mh * 32 + g * 8];
                acc[sub] = __builtin_amdgcn_mfma_f32_16x16x32_bf16(pa, bv, acc[sub], 0, 0, 0);
            }
        }
    }

    // epilogue: normalize, write ctx bf16
    #pragma unroll
    for (int sub = 0; sub < 2; ++sub)
        #pragma unroll
        for (int reg = 0; reg < 4; ++reg) {
            const int q = q0 + g * 4 + reg;
            ctx[((size_t)b * NQ + q) * DD + h * HDD + sub * 16 + c]
                = f2b(acc[sub][reg] / lrun[reg]);
        }
}

// ---------------------------------------------------------------------------
extern "C" void kernel_launch(void* const* d_in, const int* in_sizes, int n_in,
                              void* d_out, int out_size, void* d_ws, size_t ws_size,
                              hipStream_t stream)
{
    const float* amr_feats    = (const float*)d_in[0];
    const int*   amr_pad_mask = (const int*)d_in[1];
    const float* visual_feats = (const float*)d_in[2];
    const float* W_amr_qk     = (const float*)d_in[3];
    const float* W_amr_v      = (const float*)d_in[4];
    const float* W_vis_qk     = (const float*)d_in[5];
    const float* W_vis_v      = (const float*)d_in[6];
    const float* W_amr_out    = (const float*)d_in[7];
    const float* b_amr_out    = (const float*)d_in[8];
    const float* W_vis_out    = (const float*)d_in[9];
    const float* b_vis_out    = (const float*)d_in[10];

    // bf16 workspace layout (ushort units), total 19,267,584 u16 = 38.5 MB
    unsigned short* ws = (unsigned short*)d_ws;
    unsigned short* amr_fb     = ws;
    unsigned short* vis_fb     = ws + 524288;
    unsigned short* Wt_amr_qk  = ws + 4718592;
    unsigned short* Wt_amr_v   = ws + 4784128;
    unsigned short* Wt_vis_qk  = ws + 4849664;
    unsigned short* Wt_vis_v   = ws + 4915200;
    unsigned short* Wt_amr_out = ws + 4980736;
    unsigned short* Wt_vis_out = ws + 5046272;
    unsigned short* amr_qk_b   = ws + 5111808;
    unsigned short* amr_v_b    = ws + 5636096;
    unsigned short* vis_qk_b   = ws + 6160384;
    unsigned short* vis_v_b    = ws + 10354688;
    unsigned short* ctx0_b     = ws + 14548992;
    unsigned short* ctx1_b     = ws + 15073280;

    float* out0 = (float*)d_out;
    float* out1 = out0 + (size_t)BB * NN * DD;

    const float SQS = 0.4204482076268573f;  // sqrt(1/sqrt(32)) folded into BOTH qk projs

    // 0) conversions
    convert_flat<<<512, 256, 0, stream>>>(amr_feats, amr_fb);
    convert_flat<<<4096, 256, 0, stream>>>(visual_feats, vis_fb);
    WPack wp;
    wp.s[0] = W_amr_qk;  wp.d[0] = Wt_amr_qk;
    wp.s[1] = W_amr_v;   wp.d[1] = Wt_amr_v;
    wp.s[2] = W_vis_qk;  wp.d[2] = Wt_vis_qk;
    wp.s[3] = W_vis_v;   wp.d[3] = Wt_vis_v;
    wp.s[4] = W_amr_out; wp.d[4] = Wt_amr_out;
    wp.s[5] = W_vis_out; wp.d[5] = Wt_vis_out;
    convert_w<<<1536, 256, 0, stream>>>(wp);

    // 1) input projections (bf16 MFMA), sqrt(scale) folded into qk outputs
    gemm_bf16<false><<<dim3(32, 4), 256, 0, stream>>>(
        amr_fb, Wt_amr_qk, SQS, nullptr, nullptr, amr_qk_b, nullptr);
    gemm_bf16<false><<<dim3(32, 4), 256, 0, stream>>>(
        amr_fb, Wt_amr_v, 1.f, nullptr, nullptr, amr_v_b, nullptr);
    gemm_bf16<false><<<dim3(256, 4), 256, 0, stream>>>(
        vis_fb, Wt_vis_qk, SQS, nullptr, nullptr, vis_qk_b, nullptr);
    gemm_bf16<false><<<dim3(256, 4), 256, 0, stream>>>(
        vis_fb, Wt_vis_v, 1.f, nullptr, nullptr, vis_v_b, nullptr);

    // 2) attention
    attn_mfma<MM, false><<<(NN / 64) * HH * BB, 256, 0, stream>>>(
        amr_qk_b, vis_qk_b, vis_v_b, nullptr, ctx0_b, NN);
    attn_mfma<NN, true><<<(MM / 64) * HH * BB, 256, 0, stream>>>(
        vis_qk_b, amr_qk_b, amr_v_b, amr_pad_mask, ctx1_b, MM);

    // 3) output projections + bias + elementwise multiply (f32 out)
    gemm_bf16<true><<<dim3(32, 4), 256, 0, stream>>>(
        ctx0_b, Wt_amr_out, 1.f, b_amr_out, amr_feats, nullptr, out0);
    gemm_bf16<true><<<dim3(256, 4), 256, 0, stream>>>(
        ctx1_b, Wt_vis_out, 1.f, b_vis_out, visual_feats, nullptr, out1);
}

// Round 5
// 190.174 us; speedup vs baseline: 15.2612x; 1.1675x over previous
//
#include <hip/hip_runtime.h>

#define BB 4
#define NN 512
#define MM 4096
#define DD 256
#define HH 8
#define HDD 32

typedef __attribute__((ext_vector_type(8))) short bf16x8;
typedef __attribute__((ext_vector_type(4))) float f32x4;

__device__ __forceinline__ unsigned short f2b(float f) {
    union { float f; unsigned u; } v; v.f = f;
    unsigned r = v.u + 0x7fffu + ((v.u >> 16) & 1u);
    return (unsigned short)(r >> 16);
}

// ---- DPP 16-lane reductions (VALU pipe, no DS ops) ------------------------
template<int CTRL>
__device__ __forceinline__ float dpp_mov(float x) {
    return __int_as_float(__builtin_amdgcn_update_dpp(
        0, __float_as_int(x), CTRL, 0xF, 0xF, true));
}
__device__ __forceinline__ float red16_max(float x) {
    x = fmaxf(x, dpp_mov<0xB1>(x));    // quad_perm [1,0,3,2]  (xor 1)
    x = fmaxf(x, dpp_mov<0x4E>(x));    // quad_perm [2,3,0,1]  (xor 2)
    x = fmaxf(x, dpp_mov<0x141>(x));   // row_half_mirror      (cross 4)
    x = fmaxf(x, dpp_mov<0x140>(x));   // row_mirror           (cross 8)
    return x;
}
__device__ __forceinline__ float red16_add(float x) {
    x += dpp_mov<0xB1>(x);
    x += dpp_mov<0x4E>(x);
    x += dpp_mov<0x141>(x);
    x += dpp_mov<0x140>(x);
    return x;
}

// ---------------------------------------------------------------------------
// f32 -> bf16 flat conversion
// ---------------------------------------------------------------------------
__global__ __launch_bounds__(256) void convert_flat(
    const float* __restrict__ src, unsigned short* __restrict__ dst)
{
    const int i = blockIdx.x * 256 + threadIdx.x;
    const float4 v = ((const float4*)src)[i];
    ushort4 o;
    o.x = f2b(v.x); o.y = f2b(v.y); o.z = f2b(v.z); o.w = f2b(v.w);
    ((ushort4*)dst)[i] = o;
}

// ---------------------------------------------------------------------------
// Convert + transpose weights: Wt[c][k] = bf16(W[k][c])
// ---------------------------------------------------------------------------
struct WPack { const float* s[6]; unsigned short* d[6]; };
__global__ __launch_bounds__(256) void convert_w(WPack p)
{
    const int mat = blockIdx.x >> 8;
    const int k = blockIdx.x & 255;
    const int c = threadIdx.x;
    p.d[mat][(size_t)c * DD + k] = f2b(p.s[mat][(size_t)k * DD + c]);
}

// ---------------------------------------------------------------------------
// V transpose: VT[b][c(256)][SEQ] <- Xb[b][SEQ][256]
// grid: (SEQ/256, 32, B). Writes coalesced (consecutive m per lane).
// ---------------------------------------------------------------------------
template<int SEQ>
__global__ __launch_bounds__(256) void transpose_v(
    const unsigned short* __restrict__ Xb, unsigned short* __restrict__ VT)
{
    const int m = blockIdx.x * 256 + threadIdx.x;
    const int c0 = blockIdx.y * 8;
    const int b = blockIdx.z;
    const bf16x8 v = *(const bf16x8*)&Xb[((size_t)b * SEQ + m) * DD + c0];
    #pragma unroll
    for (int j = 0; j < 8; ++j)
        VT[((size_t)b * DD + c0 + j) * SEQ + m] = (unsigned short)v[j];
}

// ---------------------------------------------------------------------------
// bf16 MFMA GEMM (unchanged from round 4): C[R,256] = A[R,256] @ W
// ---------------------------------------------------------------------------
template<bool OUTPROJ>
__global__ __launch_bounds__(256) void gemm_bf16(
    const unsigned short* __restrict__ A,
    const unsigned short* __restrict__ Wt,
    float outscale,
    const float* __restrict__ bias,
    const float* __restrict__ feats,
    unsigned short* __restrict__ Cb,
    float* __restrict__ Cf)
{
    __shared__ unsigned short As[64][72];
    __shared__ unsigned short Ws[64][72];
    const int tid = threadIdx.x;
    const int lane = tid & 63, w = tid >> 6;
    const int r0 = blockIdx.x * 64, c0 = blockIdx.y * 64;
    const int rq = (w >> 1) * 32, cq = (w & 1) * 32;
    const int srow = tid >> 2, skc = (tid & 3) * 16;
    const int g = lane >> 4, cl = lane & 15;

    f32x4 acc[2][2] = {};

    for (int ks = 0; ks < DD; ks += 64) {
        __syncthreads();
        {
            const unsigned short* ga = &A[(size_t)(r0 + srow) * DD + ks + skc];
            *(bf16x8*)&As[srow][skc]     = *(const bf16x8*)ga;
            *(bf16x8*)&As[srow][skc + 8] = *(const bf16x8*)(ga + 8);
            const unsigned short* gw = &Wt[(size_t)(c0 + srow) * DD + ks + skc];
            *(bf16x8*)&Ws[srow][skc]     = *(const bf16x8*)gw;
            *(bf16x8*)&Ws[srow][skc + 8] = *(const bf16x8*)(gw + 8);
        }
        __syncthreads();
        #pragma unroll
        for (int kh = 0; kh < 2; ++kh) {
            const int kk = kh * 32 + g * 8;
            const bf16x8 a0 = *(const bf16x8*)&As[rq + cl][kk];
            const bf16x8 a1 = *(const bf16x8*)&As[rq + 16 + cl][kk];
            const bf16x8 b0 = *(const bf16x8*)&Ws[cq + cl][kk];
            const bf16x8 b1 = *(const bf16x8*)&Ws[cq + 16 + cl][kk];
            acc[0][0] = __builtin_amdgcn_mfma_f32_16x16x32_bf16(a0, b0, acc[0][0], 0, 0, 0);
            acc[0][1] = __builtin_amdgcn_mfma_f32_16x16x32_bf16(a0, b1, acc[0][1], 0, 0, 0);
            acc[1][0] = __builtin_amdgcn_mfma_f32_16x16x32_bf16(a1, b0, acc[1][0], 0, 0, 0);
            acc[1][1] = __builtin_amdgcn_mfma_f32_16x16x32_bf16(a1, b1, acc[1][1], 0, 0, 0);
        }
    }

    #pragma unroll
    for (int sr = 0; sr < 2; ++sr)
    #pragma unroll
    for (int sc = 0; sc < 2; ++sc) {
        const int col = c0 + cq + sc * 16 + cl;
        #pragma unroll
        for (int reg = 0; reg < 4; ++reg) {
            const int row = r0 + rq + sr * 16 + g * 4 + reg;
            const size_t idx = (size_t)row * DD + col;
            if (OUTPROJ) {
                Cf[idx] = (acc[sr][sc][reg] + bias[col]) * feats[idx];
            } else {
                Cb[idx] = f2b(acc[sr][sc][reg] * outscale);
            }
        }
    }
}

// ---------------------------------------------------------------------------
// MFMA flash attention, barrier-free main loop.
// K read as B-frags from global [b][SEQK][256]; V from pre-transposed
// VT [b][256][SEQK]. Scores arrive in exp2 domain (log2e folded into proj).
// SPLIT>1: write f32 partials (m, l, acc) per (block), combined later.
// ---------------------------------------------------------------------------
template<int SEQK, int SPLIT, bool HAS_MASK>
__global__ __launch_bounds__(256) void attn_mfma(
    const unsigned short* __restrict__ Qb,
    const unsigned short* __restrict__ Kb,
    const unsigned short* __restrict__ VTb,
    const int* __restrict__ mask,
    unsigned short* __restrict__ ctx,
    float* __restrict__ Pm, float* __restrict__ Pl, float* __restrict__ Pacc,
    int NQ)
{
    constexpr int KCHUNK = SEQK / SPLIT;
    constexpr int NT = KCHUNK / 64;

    __shared__ unsigned short Pw[4][16][88];   // per-wave P, pitch 88 u16
    __shared__ float maskadd[HAS_MASK ? SEQK : 4];

    const int tid = threadIdx.x;
    const int lane = tid & 63, w = tid >> 6;
    const int g = lane >> 4, cl = lane & 15;

    const int nqt = NQ / 64;
    int bi = blockIdx.x;
    const int sp = bi % SPLIT; bi /= SPLIT;
    const int qt = bi % nqt;   bi /= nqt;
    const int h  = bi % HH;
    const int b  = bi / HH;
    const int q0 = qt * 64 + w * 16;
    const int kv0 = sp * KCHUNK;

    if (HAS_MASK) {
        for (int i = tid; i < SEQK; i += 256)
            maskadd[i] = mask[b * SEQK + i] ? -1e30f : 0.f;
        __syncthreads();
    }

    const bf16x8 aq = *(const bf16x8*)
        &Qb[((size_t)b * NQ + q0 + cl) * DD + h * HDD + g * 8];
    const unsigned short* Kbase = &Kb[(size_t)b * SEQK * DD + h * HDD + g * 8];
    const unsigned short* Vbase = &VTb[((size_t)b * DD + h * HDD) * SEQK];

    float mrun[4], lrun[4];
    #pragma unroll
    for (int r = 0; r < 4; ++r) { mrun[r] = -1e30f; lrun[r] = 0.f; }
    f32x4 acc[2] = {};

    for (int t = 0; t < NT; ++t) {
        const int m0 = kv0 + t * 64;

        // QK^T: S[16q][64key] in 4 D-frags (B-frags straight from global/L1)
        f32x4 s[4];
        #pragma unroll
        for (int kf = 0; kf < 4; ++kf) {
            const bf16x8 bk = *(const bf16x8*)&Kbase[(size_t)(m0 + kf * 16 + cl) * DD];
            const f32x4 z = {0.f, 0.f, 0.f, 0.f};
            s[kf] = __builtin_amdgcn_mfma_f32_16x16x32_bf16(aq, bk, z, 0, 0, 0);
        }

        // mask + in-register fold over kf, then DPP reduce over 16 key-lanes
        float lm[4] = {-1e30f, -1e30f, -1e30f, -1e30f};
        #pragma unroll
        for (int kf = 0; kf < 4; ++kf) {
            const float madd = HAS_MASK ? maskadd[m0 + kf * 16 + cl] : 0.f;
            #pragma unroll
            for (int reg = 0; reg < 4; ++reg) {
                s[kf][reg] += madd;
                lm[reg] = fmaxf(lm[reg], s[kf][reg]);
            }
        }
        #pragma unroll
        for (int reg = 0; reg < 4; ++reg) lm[reg] = red16_max(lm[reg]);

        // online-softmax update (exp2 domain)
        float sf[4], rs[4];
        #pragma unroll
        for (int reg = 0; reg < 4; ++reg) {
            const float mnew = fmaxf(mrun[reg], lm[reg]);
            sf[reg] = exp2f(mrun[reg] - mnew);
            mrun[reg] = mnew;
            rs[reg] = 0.f;
        }
        #pragma unroll
        for (int kf = 0; kf < 4; ++kf)
            #pragma unroll
            for (int reg = 0; reg < 4; ++reg) {
                const float p = exp2f(s[kf][reg] - mrun[reg]);
                s[kf][reg] = p;
                rs[reg] += p;
            }
        #pragma unroll
        for (int reg = 0; reg < 4; ++reg) {
            rs[reg] = red16_add(rs[reg]);
            lrun[reg] = lrun[reg] * sf[reg] + rs[reg];
        }
        #pragma unroll
        for (int sub = 0; sub < 2; ++sub)
            #pragma unroll
            for (int reg = 0; reg < 4; ++reg)
                acc[sub][reg] *= sf[reg];

        // P -> wave-private LDS (D-layout -> A-layout transpose)
        #pragma unroll
        for (int kf = 0; kf < 4; ++kf)
            #pragma unroll
            for (int reg = 0; reg < 4; ++reg)
                Pw[w][g * 4 + reg][kf * 16 + cl] = f2b(s[kf][reg]);

        // PV: acc[16q][32c] += P[16q][64m] x V[64m][32c]  (V frags from global)
        #pragma unroll
        for (int mh = 0; mh < 2; ++mh) {
            const bf16x8 pa = *(const bf16x8*)&Pw[w][cl][mh * 32 + g * 8];
            #pragma unroll
            for (int sub = 0; sub < 2; ++sub) {
                const bf16x8 bv = *(const bf16x8*)
                    &Vbase[(size_t)(sub * 16 + cl) * SEQK + m0 + mh * 32 + g * 8];
                acc[sub] = __builtin_amdgcn_mfma_f32_16x16x32_bf16(pa, bv, acc[sub], 0, 0, 0);
            }
        }
    }

    if (SPLIT > 1) {
        const int pb = blockIdx.x;
        #pragma unroll
        for (int sub = 0; sub < 2; ++sub)
            #pragma unroll
            for (int reg = 0; reg < 4; ++reg)
                Pacc[((size_t)pb * 64 + w * 16 + g * 4 + reg) * 32 + sub * 16 + cl]
                    = acc[sub][reg];
        if (cl == 0) {
            #pragma unroll
            for (int reg = 0; reg < 4; ++reg) {
                Pm[(size_t)pb * 64 + w * 16 + g * 4 + reg] = mrun[reg];
                Pl[(size_t)pb * 64 + w * 16 + g * 4 + reg] = lrun[reg];
            }
        }
    } else {
        #pragma unroll
        for (int sub = 0; sub < 2; ++sub)
            #pragma unroll
            for (int reg = 0; reg < 4; ++reg) {
                const int q = q0 + g * 4 + reg;
                ctx[((size_t)b * NQ + q) * DD + h * HDD + sub * 16 + cl]
                    = f2b(acc[sub][reg] / lrun[reg]);
            }
    }
}

// ---------------------------------------------------------------------------
// Combine SPLIT=4 partials -> bf16 ctx  (dir A). grid = B*HH*(NN/64), 256 thr.
// ---------------------------------------------------------------------------
__global__ __launch_bounds__(256) void combine_split(
    const float* __restrict__ Pm, const float* __restrict__ Pl,
    const float* __restrict__ Pacc, unsigned short* __restrict__ ctx)
{
    const int tid = threadIdx.x;
    const int q = tid >> 2, cp = tid & 3;
    const int bqt = blockIdx.x;
    const int pb0 = bqt * 4;
    const int qt = bqt % 8;
    const int bh = bqt / 8;
    const int h = bh % HH, b = bh / HH;

    float m[4], l[4];
    #pragma unroll
    for (int sp = 0; sp < 4; ++sp) {
        m[sp] = Pm[(size_t)(pb0 + sp) * 64 + q];
        l[sp] = Pl[(size_t)(pb0 + sp) * 64 + q];
    }
    float M = fmaxf(fmaxf(m[0], m[1]), fmaxf(m[2], m[3]));
    float wgt[4], denom = 0.f;
    #pragma unroll
    for (int sp = 0; sp < 4; ++sp) {
        wgt[sp] = exp2f(m[sp] - M);
        denom += l[sp] * wgt[sp];
    }
    const float inv = 1.f / denom;

    float o[8] = {};
    #pragma unroll
    for (int sp = 0; sp < 4; ++sp) {
        const float* a = &Pacc[((size_t)(pb0 + sp) * 64 + q) * 32 + cp * 8];
        const float4 a0 = *(const float4*)a;
        const float4 a1 = *(const float4*)(a + 4);
        o[0] += a0.x * wgt[sp]; o[1] += a0.y * wgt[sp];
        o[2] += a0.z * wgt[sp]; o[3] += a0.w * wgt[sp];
        o[4] += a1.x * wgt[sp]; o[5] += a1.y * wgt[sp];
        o[6] += a1.z * wgt[sp]; o[7] += a1.w * wgt[sp];
    }
    ushort4 u0, u1;
    u0.x = f2b(o[0] * inv); u0.y = f2b(o[1] * inv);
    u0.z = f2b(o[2] * inv); u0.w = f2b(o[3] * inv);
    u1.x = f2b(o[4] * inv); u1.y = f2b(o[5] * inv);
    u1.z = f2b(o[6] * inv); u1.w = f2b(o[7] * inv);
    unsigned short* dst = &ctx[((size_t)b * NN + qt * 64 + q) * DD + h * HDD + cp * 8];
    *(ushort4*)dst = u0;
    *(ushort4*)(dst + 4) = u1;
}

// ---------------------------------------------------------------------------
extern "C" void kernel_launch(void* const* d_in, const int* in_sizes, int n_in,
                              void* d_out, int out_size, void* d_ws, size_t ws_size,
                              hipStream_t stream)
{
    const float* amr_feats    = (const float*)d_in[0];
    const int*   amr_pad_mask = (const int*)d_in[1];
    const float* visual_feats = (const float*)d_in[2];
    const float* W_amr_qk     = (const float*)d_in[3];
    const float* W_amr_v      = (const float*)d_in[4];
    const float* W_vis_qk     = (const float*)d_in[5];
    const float* W_vis_v      = (const float*)d_in[6];
    const float* W_amr_out    = (const float*)d_in[7];
    const float* b_amr_out    = (const float*)d_in[8];
    const float* W_vis_out    = (const float*)d_in[9];
    const float* b_vis_out    = (const float*)d_in[10];

    // bf16 workspace (u16 offsets), total 48.0 MB
    unsigned short* ws = (unsigned short*)d_ws;
    unsigned short* amr_fb     = ws;                    // dead after GEMM 1-2
    unsigned short* vis_fb     = ws + 524288;           // dead after GEMM 3-4
    unsigned short* Wt_amr_qk  = ws + 4718592;
    unsigned short* Wt_amr_v   = ws + 4784128;
    unsigned short* Wt_vis_qk  = ws + 4849664;
    unsigned short* Wt_vis_v   = ws + 4915200;
    unsigned short* Wt_amr_out = ws + 4980736;
    unsigned short* Wt_vis_out = ws + 5046272;
    unsigned short* amr_qk_b   = ws + 5111808;
    unsigned short* amr_v_b    = ws + 5636096;
    unsigned short* vis_qk_b   = ws + 6160384;
    unsigned short* vis_v_b    = ws + 10354688;
    unsigned short* ctx0_b     = ws + 14548992;
    unsigned short* ctx1_b     = ws + 15073280;
    unsigned short* VT_vis     = ws + 19267584;
    unsigned short* VT_amr     = ws + 23461888;
    // split-K partials alias the dead amr_fb/vis_fb region
    float* Pm   = (float*)(ws);            // 1024*64 f32
    float* Pl   = (float*)(ws + 131072);   // 1024*64 f32
    float* Pacc = (float*)(ws + 262144);   // 1024*64*32 f32, ends @4456448 u16

    float* out0 = (float*)d_out;
    float* out1 = out0 + (size_t)BB * NN * DD;

    // sqrt( HD^-0.5 * log2(e) ) folded into BOTH qk projections -> exp2 domain
    const float SQS = 0.50500976f;

    // 0) conversions
    convert_flat<<<512, 256, 0, stream>>>(amr_feats, amr_fb);
    convert_flat<<<4096, 256, 0, stream>>>(visual_feats, vis_fb);
    WPack wp;
    wp.s[0] = W_amr_qk;  wp.d[0] = Wt_amr_qk;
    wp.s[1] = W_amr_v;   wp.d[1] = Wt_amr_v;
    wp.s[2] = W_vis_qk;  wp.d[2] = Wt_vis_qk;
    wp.s[3] = W_vis_v;   wp.d[3] = Wt_vis_v;
    wp.s[4] = W_amr_out; wp.d[4] = Wt_amr_out;
    wp.s[5] = W_vis_out; wp.d[5] = Wt_vis_out;
    convert_w<<<1536, 256, 0, stream>>>(wp);

    // 1) input projections
    gemm_bf16<false><<<dim3(32, 4), 256, 0, stream>>>(
        amr_fb, Wt_amr_qk, SQS, nullptr, nullptr, amr_qk_b, nullptr);
    gemm_bf16<false><<<dim3(32, 4), 256, 0, stream>>>(
        amr_fb, Wt_amr_v, 1.f, nullptr, nullptr, amr_v_b, nullptr);
    gemm_bf16<false><<<dim3(256, 4), 256, 0, stream>>>(
        vis_fb, Wt_vis_qk, SQS, nullptr, nullptr, vis_qk_b, nullptr);
    gemm_bf16<false><<<dim3(256, 4), 256, 0, stream>>>(
        vis_fb, Wt_vis_v, 1.f, nullptr, nullptr, vis_v_b, nullptr);

    // 1b) V transposes for the PV B-operand
    transpose_v<MM><<<dim3(16, 32, 4), 256, 0, stream>>>(vis_v_b, VT_vis);
    transpose_v<NN><<<dim3(2, 32, 4), 256, 0, stream>>>(amr_v_b, VT_amr);

    // 2) attention
    //    dir A: Q=amr(512), K/V=vis(4096), split-K x4 -> partials -> combine
    attn_mfma<MM, 4, false><<<(NN / 64) * HH * BB * 4, 256, 0, stream>>>(
        amr_qk_b, vis_qk_b, VT_vis, nullptr, nullptr, Pm, Pl, Pacc, NN);
    combine_split<<<(NN / 64) * HH * BB, 256, 0, stream>>>(Pm, Pl, Pacc, ctx0_b);
    //    dir B: Q=vis(4096), K/V=amr(512), key mask
    attn_mfma<NN, 1, true><<<(MM / 64) * HH * BB, 256, 0, stream>>>(
        vis_qk_b, amr_qk_b, VT_amr, amr_pad_mask, ctx1_b,
        nullptr, nullptr, nullptr, MM);

    // 3) output projections + bias + elementwise multiply (f32 out)
    gemm_bf16<true><<<dim3(32, 4), 256, 0, stream>>>(
        ctx0_b, Wt_amr_out, 1.f, b_amr_out, amr_feats, nullptr, out0);
    gemm_bf16<true><<<dim3(256, 4), 256, 0, stream>>>(
        ctx1_b, Wt_vis_out, 1.f, b_vis_out, visual_feats, nullptr, out1);
}

// Round 6
// 183.406 us; speedup vs baseline: 15.8243x; 1.0369x over previous
//
#include <hip/hip_runtime.h>

#define BB 4
#define NN 512
#define MM 4096
#define DD 256
#define HH 8
#define HDD 32

typedef __attribute__((ext_vector_type(8))) short bf16x8;
typedef __attribute__((ext_vector_type(4))) float f32x4;

__device__ __forceinline__ unsigned short f2b(float f) {
    union { float f; unsigned u; } v; v.f = f;
    unsigned r = v.u + 0x7fffu + ((v.u >> 16) & 1u);
    return (unsigned short)(r >> 16);
}

// ---- DPP 16-lane add reduction (VALU pipe, no DS ops) ---------------------
template<int CTRL>
__device__ __forceinline__ float dpp_mov(float x) {
    return __int_as_float(__builtin_amdgcn_update_dpp(
        0, __float_as_int(x), CTRL, 0xF, 0xF, true));
}
__device__ __forceinline__ float red16_add(float x) {
    x += dpp_mov<0xB1>(x);     // quad_perm xor1
    x += dpp_mov<0x4E>(x);     // quad_perm xor2
    x += dpp_mov<0x141>(x);    // row_half_mirror
    x += dpp_mov<0x140>(x);    // row_mirror
    return x;
}

// ---------------------------------------------------------------------------
// f32 -> bf16 flat conversion
// ---------------------------------------------------------------------------
__global__ __launch_bounds__(256) void convert_flat(
    const float* __restrict__ src, unsigned short* __restrict__ dst)
{
    const int i = blockIdx.x * 256 + threadIdx.x;
    const float4 v = ((const float4*)src)[i];
    ushort4 o;
    o.x = f2b(v.x); o.y = f2b(v.y); o.z = f2b(v.z); o.w = f2b(v.w);
    ((ushort4*)dst)[i] = o;
}

// ---------------------------------------------------------------------------
// Convert + transpose weights: Wt[c][k] = bf16(W[k][c])
// ---------------------------------------------------------------------------
struct WPack { const float* s[6]; unsigned short* d[6]; };
__global__ __launch_bounds__(256) void convert_w(WPack p)
{
    const int mat = blockIdx.x >> 8;
    const int k = blockIdx.x & 255;
    const int c = threadIdx.x;
    p.d[mat][(size_t)c * DD + k] = f2b(p.s[mat][(size_t)k * DD + c]);
}

// ---------------------------------------------------------------------------
// V transpose: VT[b][c(256)][SEQ] <- Xb[b][SEQ][256]
// ---------------------------------------------------------------------------
template<int SEQ>
__global__ __launch_bounds__(256) void transpose_v(
    const unsigned short* __restrict__ Xb, unsigned short* __restrict__ VT)
{
    const int m = blockIdx.x * 256 + threadIdx.x;
    const int c0 = blockIdx.y * 8;
    const int b = blockIdx.z;
    const bf16x8 v = *(const bf16x8*)&Xb[((size_t)b * SEQ + m) * DD + c0];
    #pragma unroll
    for (int j = 0; j < 8; ++j)
        VT[((size_t)b * DD + c0 + j) * SEQ + m] = (unsigned short)v[j];
}

// ---------------------------------------------------------------------------
// bf16 MFMA GEMM: C[R,256] = A[R,256] @ W  (Wt pre-transposed)
// ---------------------------------------------------------------------------
template<bool OUTPROJ>
__global__ __launch_bounds__(256) void gemm_bf16(
    const unsigned short* __restrict__ A,
    const unsigned short* __restrict__ Wt,
    float outscale,
    const float* __restrict__ bias,
    const float* __restrict__ feats,
    unsigned short* __restrict__ Cb,
    float* __restrict__ Cf)
{
    __shared__ unsigned short As[64][72];
    __shared__ unsigned short Ws[64][72];
    const int tid = threadIdx.x;
    const int lane = tid & 63, w = tid >> 6;
    const int r0 = blockIdx.x * 64, c0 = blockIdx.y * 64;
    const int rq = (w >> 1) * 32, cq = (w & 1) * 32;
    const int srow = tid >> 2, skc = (tid & 3) * 16;
    const int g = lane >> 4, cl = lane & 15;

    f32x4 acc[2][2] = {};

    for (int ks = 0; ks < DD; ks += 64) {
        __syncthreads();
        {
            const unsigned short* ga = &A[(size_t)(r0 + srow) * DD + ks + skc];
            *(bf16x8*)&As[srow][skc]     = *(const bf16x8*)ga;
            *(bf16x8*)&As[srow][skc + 8] = *(const bf16x8*)(ga + 8);
            const unsigned short* gw = &Wt[(size_t)(c0 + srow) * DD + ks + skc];
            *(bf16x8*)&Ws[srow][skc]     = *(const bf16x8*)gw;
            *(bf16x8*)&Ws[srow][skc + 8] = *(const bf16x8*)(gw + 8);
        }
        __syncthreads();
        #pragma unroll
        for (int kh = 0; kh < 2; ++kh) {
            const int kk = kh * 32 + g * 8;
            const bf16x8 a0 = *(const bf16x8*)&As[rq + cl][kk];
            const bf16x8 a1 = *(const bf16x8*)&As[rq + 16 + cl][kk];
            const bf16x8 b0 = *(const bf16x8*)&Ws[cq + cl][kk];
            const bf16x8 b1 = *(const bf16x8*)&Ws[cq + 16 + cl][kk];
            acc[0][0] = __builtin_amdgcn_mfma_f32_16x16x32_bf16(a0, b0, acc[0][0], 0, 0, 0);
            acc[0][1] = __builtin_amdgcn_mfma_f32_16x16x32_bf16(a0, b1, acc[0][1], 0, 0, 0);
            acc[1][0] = __builtin_amdgcn_mfma_f32_16x16x32_bf16(a1, b0, acc[1][0], 0, 0, 0);
            acc[1][1] = __builtin_amdgcn_mfma_f32_16x16x32_bf16(a1, b1, acc[1][1], 0, 0, 0);
        }
    }

    #pragma unroll
    for (int sr = 0; sr < 2; ++sr)
    #pragma unroll
    for (int sc = 0; sc < 2; ++sc) {
        const int col = c0 + cq + sc * 16 + cl;
        #pragma unroll
        for (int reg = 0; reg < 4; ++reg) {
            const int row = r0 + rq + sr * 16 + g * 4 + reg;
            const size_t idx = (size_t)row * DD + col;
            if (OUTPROJ) {
                Cf[idx] = (acc[sr][sc][reg] + bias[col]) * feats[idx];
            } else {
                Cb[idx] = f2b(acc[sr][sc][reg] * outscale);
            }
        }
    }
}

// ---------------------------------------------------------------------------
// Attention body: no-max softmax (exp2-domain scores, |s| << 120 so exp2 is
// overflow-safe; result identical to max-subtracted softmax up to fp).
// Per-lane l accumulation; single DPP reduce at the end.
// ---------------------------------------------------------------------------
template<int SEQK, int SPLIT, bool HAS_MASK>
__device__ __forceinline__ void attn_body(
    int bid,
    const unsigned short* __restrict__ Qb,
    const unsigned short* __restrict__ Kb,
    const unsigned short* __restrict__ VTb,
    const int* __restrict__ mask,
    unsigned short* __restrict__ ctx,
    float* __restrict__ Pl, float* __restrict__ Pacc,
    int NQ,
    unsigned short (*Pw)[16][88], float* maskadd)
{
    constexpr int KCHUNK = SEQK / SPLIT;
    constexpr int NT = KCHUNK / 64;

    const int tid = threadIdx.x;
    const int lane = tid & 63, w = tid >> 6;
    const int g = lane >> 4, cl = lane & 15;

    const int nqt = NQ / 64;
    int bi = bid;
    const int sp = bi % SPLIT; bi /= SPLIT;
    const int qt = bi % nqt;   bi /= nqt;
    const int h  = bi % HH;
    const int b  = bi / HH;
    const int q0 = qt * 64 + w * 16;
    const int kv0 = sp * KCHUNK;

    if (HAS_MASK) {
        for (int i = tid; i < SEQK; i += 256)
            maskadd[i] = mask[b * SEQK + i] ? -1e30f : 0.f;
        __syncthreads();
    }

    const bf16x8 aq = *(const bf16x8*)
        &Qb[((size_t)b * NQ + q0 + cl) * DD + h * HDD + g * 8];
    const unsigned short* Kbase = &Kb[(size_t)b * SEQK * DD + h * HDD + g * 8];
    const unsigned short* Vbase = &VTb[((size_t)b * DD + h * HDD) * SEQK];

    float lsum[4] = {0.f, 0.f, 0.f, 0.f};
    f32x4 acc[2] = {};

    for (int t = 0; t < NT; ++t) {
        const int m0 = kv0 + t * 64;

        // QK^T: S[16q][64key] in 4 D-frags (B-frags straight from global/L1)
        f32x4 s[4];
        #pragma unroll
        for (int kf = 0; kf < 4; ++kf) {
            const bf16x8 bk = *(const bf16x8*)&Kbase[(size_t)(m0 + kf * 16 + cl) * DD];
            const f32x4 z = {0.f, 0.f, 0.f, 0.f};
            s[kf] = __builtin_amdgcn_mfma_f32_16x16x32_bf16(aq, bk, z, 0, 0, 0);
        }

        // P = exp2(s [+mask]), accumulate l per-lane, store P (bf16) to LDS
        #pragma unroll
        for (int kf = 0; kf < 4; ++kf) {
            const float madd = HAS_MASK ? maskadd[m0 + kf * 16 + cl] : 0.f;
            #pragma unroll
            for (int reg = 0; reg < 4; ++reg) {
                const float p = exp2f(s[kf][reg] + madd);
                lsum[reg] += p;
                Pw[w][g * 4 + reg][kf * 16 + cl] = f2b(p);
            }
        }

        // PV: acc[16q][32c] += P[16q][64m] x V[64m][32c]
        #pragma unroll
        for (int mh = 0; mh < 2; ++mh) {
            const bf16x8 pa = *(const bf16x8*)&Pw[w][cl][mh * 32 + g * 8];
            #pragma unroll
            for (int sub = 0; sub < 2; ++sub) {
                const bf16x8 bv = *(const bf16x8*)
                    &Vbase[(size_t)(sub * 16 + cl) * SEQK + m0 + mh * 32 + g * 8];
                acc[sub] = __builtin_amdgcn_mfma_f32_16x16x32_bf16(pa, bv, acc[sub], 0, 0, 0);
            }
        }
    }

    // single row-sum reduce over the 16 key-lanes
    #pragma unroll
    for (int reg = 0; reg < 4; ++reg) lsum[reg] = red16_add(lsum[reg]);

    if (SPLIT > 1) {
        const int pb = bid;
        #pragma unroll
        for (int sub = 0; sub < 2; ++sub)
            #pragma unroll
            for (int reg = 0; reg < 4; ++reg)
                Pacc[((size_t)pb * 64 + w * 16 + g * 4 + reg) * 32 + sub * 16 + cl]
                    = acc[sub][reg];
        if (cl == 0) {
            #pragma unroll
            for (int reg = 0; reg < 4; ++reg)
                Pl[(size_t)pb * 64 + w * 16 + g * 4 + reg] = lsum[reg];
        }
    } else {
        #pragma unroll
        for (int sub = 0; sub < 2; ++sub)
            #pragma unroll
            for (int reg = 0; reg < 4; ++reg) {
                const int q = q0 + g * 4 + reg;
                ctx[((size_t)b * NQ + q) * DD + h * HDD + sub * 16 + cl]
                    = f2b(acc[sub][reg] / lsum[reg]);
            }
    }
}

// ---------------------------------------------------------------------------
// Fused launch: dir A (blocks 0..1023, split-K x4) + dir B (blocks 1024..3071)
// run concurrently — both are latency-bound, serializing them wastes the GPU.
// ---------------------------------------------------------------------------
__global__ __launch_bounds__(256) void attn_fused(
    const unsigned short* __restrict__ amr_qk,
    const unsigned short* __restrict__ vis_qk,
    const unsigned short* __restrict__ VT_vis,
    const unsigned short* __restrict__ VT_amr,
    const int* __restrict__ mask,
    unsigned short* __restrict__ ctx1,
    float* __restrict__ Pl, float* __restrict__ Pacc)
{
    __shared__ unsigned short Pw[4][16][88];
    __shared__ float maskadd[NN];
    constexpr int NA = (NN / 64) * HH * BB * 4;   // 1024 dir-A blocks
    if (blockIdx.x < NA) {
        attn_body<MM, 4, false>(blockIdx.x, amr_qk, vis_qk, VT_vis, nullptr,
                                nullptr, Pl, Pacc, NN, Pw, maskadd);
    } else {
        attn_body<NN, 1, true>(blockIdx.x - NA, vis_qk, amr_qk, VT_amr, mask,
                               ctx1, nullptr, nullptr, MM, Pw, maskadd);
    }
}

// ---------------------------------------------------------------------------
// Combine SPLIT=4 partials -> bf16 ctx (dir A): out = sum(acc) / sum(l)
// ---------------------------------------------------------------------------
__global__ __launch_bounds__(256) void combine_split(
    const float* __restrict__ Pl, const float* __restrict__ Pacc,
    unsigned short* __restrict__ ctx)
{
    const int tid = threadIdx.x;
    const int q = tid >> 2, cp = tid & 3;
    const int bqt = blockIdx.x;
    const int pb0 = bqt * 4;
    const int qt = bqt % 8;
    const int bh = bqt / 8;
    const int h = bh % HH, b = bh / HH;

    float denom = 0.f;
    #pragma unroll
    for (int sp = 0; sp < 4; ++sp)
        denom += Pl[(size_t)(pb0 + sp) * 64 + q];
    const float inv = 1.f / denom;

    float o[8] = {};
    #pragma unroll
    for (int sp = 0; sp < 4; ++sp) {
        const float* a = &Pacc[((size_t)(pb0 + sp) * 64 + q) * 32 + cp * 8];
        const float4 a0 = *(const float4*)a;
        const float4 a1 = *(const float4*)(a + 4);
        o[0] += a0.x; o[1] += a0.y; o[2] += a0.z; o[3] += a0.w;
        o[4] += a1.x; o[5] += a1.y; o[6] += a1.z; o[7] += a1.w;
    }
    ushort4 u0, u1;
    u0.x = f2b(o[0] * inv); u0.y = f2b(o[1] * inv);
    u0.z = f2b(o[2] * inv); u0.w = f2b(o[3] * inv);
    u1.x = f2b(o[4] * inv); u1.y = f2b(o[5] * inv);
    u1.z = f2b(o[6] * inv); u1.w = f2b(o[7] * inv);
    unsigned short* dst = &ctx[((size_t)b * NN + qt * 64 + q) * DD + h * HDD + cp * 8];
    *(ushort4*)dst = u0;
    *(ushort4*)(dst + 4) = u1;
}

// ---------------------------------------------------------------------------
extern "C" void kernel_launch(void* const* d_in, const int* in_sizes, int n_in,
                              void* d_out, int out_size, void* d_ws, size_t ws_size,
                              hipStream_t stream)
{
    const float* amr_feats    = (const float*)d_in[0];
    const int*   amr_pad_mask = (const int*)d_in[1];
    const float* visual_feats = (const float*)d_in[2];
    const float* W_amr_qk     = (const float*)d_in[3];
    const float* W_amr_v      = (const float*)d_in[4];
    const float* W_vis_qk     = (const float*)d_in[5];
    const float* W_vis_v      = (const float*)d_in[6];
    const float* W_amr_out    = (const float*)d_in[7];
    const float* b_amr_out    = (const float*)d_in[8];
    const float* W_vis_out    = (const float*)d_in[9];
    const float* b_vis_out    = (const float*)d_in[10];

    // bf16 workspace (u16 offsets), total 48.0 MB
    unsigned short* ws = (unsigned short*)d_ws;
    unsigned short* amr_fb     = ws;                    // dead after GEMM 1-2
    unsigned short* vis_fb     = ws + 524288;           // dead after GEMM 3-4
    unsigned short* Wt_amr_qk  = ws + 4718592;
    unsigned short* Wt_amr_v   = ws + 4784128;
    unsigned short* Wt_vis_qk  = ws + 4849664;
    unsigned short* Wt_vis_v   = ws + 4915200;
    unsigned short* Wt_amr_out = ws + 4980736;
    unsigned short* Wt_vis_out = ws + 5046272;
    unsigned short* amr_qk_b   = ws + 5111808;
    unsigned short* amr_v_b    = ws + 5636096;
    unsigned short* vis_qk_b   = ws + 6160384;
    unsigned short* vis_v_b    = ws + 10354688;
    unsigned short* ctx0_b     = ws + 14548992;
    unsigned short* ctx1_b     = ws + 15073280;
    unsigned short* VT_vis     = ws + 19267584;
    unsigned short* VT_amr     = ws + 23461888;
    // split-K partials alias the dead amr_fb/vis_fb region
    float* Pl   = (float*)(ws);            // 1024*64 f32
    float* Pacc = (float*)(ws + 262144);   // 1024*64*32 f32

    float* out0 = (float*)d_out;
    float* out1 = out0 + (size_t)BB * NN * DD;

    // sqrt( HD^-0.5 * log2(e) ) folded into BOTH qk projections -> exp2 domain
    const float SQS = 0.50500976f;

    // 0) conversions
    convert_flat<<<512, 256, 0, stream>>>(amr_feats, amr_fb);
    convert_flat<<<4096, 256, 0, stream>>>(visual_feats, vis_fb);
    WPack wp;
    wp.s[0] = W_amr_qk;  wp.d[0] = Wt_amr_qk;
    wp.s[1] = W_amr_v;   wp.d[1] = Wt_amr_v;
    wp.s[2] = W_vis_qk;  wp.d[2] = Wt_vis_qk;
    wp.s[3] = W_vis_v;   wp.d[3] = Wt_vis_v;
    wp.s[4] = W_amr_out; wp.d[4] = Wt_amr_out;
    wp.s[5] = W_vis_out; wp.d[5] = Wt_vis_out;
    convert_w<<<1536, 256, 0, stream>>>(wp);

    // 1) input projections
    gemm_bf16<false><<<dim3(32, 4), 256, 0, stream>>>(
        amr_fb, Wt_amr_qk, SQS, nullptr, nullptr, amr_qk_b, nullptr);
    gemm_bf16<false><<<dim3(32, 4), 256, 0, stream>>>(
        amr_fb, Wt_amr_v, 1.f, nullptr, nullptr, amr_v_b, nullptr);
    gemm_bf16<false><<<dim3(256, 4), 256, 0, stream>>>(
        vis_fb, Wt_vis_qk, SQS, nullptr, nullptr, vis_qk_b, nullptr);
    gemm_bf16<false><<<dim3(256, 4), 256, 0, stream>>>(
        vis_fb, Wt_vis_v, 1.f, nullptr, nullptr, vis_v_b, nullptr);

    // 1b) V transposes for the PV B-operand
    transpose_v<MM><<<dim3(16, 32, 4), 256, 0, stream>>>(vis_v_b, VT_vis);
    transpose_v<NN><<<dim3(2, 32, 4), 256, 0, stream>>>(amr_v_b, VT_amr);

    // 2) both attention directions in ONE launch (overlap)
    attn_fused<<<3072, 256, 0, stream>>>(
        amr_qk_b, vis_qk_b, VT_vis, VT_amr, amr_pad_mask, ctx1_b, Pl, Pacc);
    combine_split<<<(NN / 64) * HH * BB, 256, 0, stream>>>(Pl, Pacc, ctx0_b);

    // 3) output projections + bias + elementwise multiply (f32 out)
    gemm_bf16<true><<<dim3(32, 4), 256, 0, stream>>>(
        ctx0_b, Wt_amr_out, 1.f, b_amr_out, amr_feats, nullptr, out0);
    gemm_bf16<true><<<dim3(256, 4), 256, 0, stream>>>(
        ctx1_b, Wt_vis_out, 1.f, b_vis_out, visual_feats, nullptr, out1);
}

// Round 7
// 133.323 us; speedup vs baseline: 21.7688x; 1.3757x over previous
//
#include <hip/hip_runtime.h>

#define BB 4
#define NN 512
#define MM 4096
#define DD 256
#define HH 8
#define HDD 32

typedef __attribute__((ext_vector_type(8))) short bf16x8;
typedef __attribute__((ext_vector_type(4))) float f32x4;

__device__ __forceinline__ unsigned short f2b(float f) {
    union { float f; unsigned u; } v; v.f = f;
    unsigned r = v.u + 0x7fffu + ((v.u >> 16) & 1u);
    return (unsigned short)(r >> 16);
}
__device__ __forceinline__ float b2f(unsigned short u) {
    union { unsigned u; float f; } v; v.u = ((unsigned)u) << 16;
    return v.f;
}

// ---- DPP 16-lane add reduction (VALU pipe, no DS ops) ---------------------
template<int CTRL>
__device__ __forceinline__ float dpp_mov(float x) {
    return __int_as_float(__builtin_amdgcn_update_dpp(
        0, __float_as_int(x), CTRL, 0xF, 0xF, true));
}
__device__ __forceinline__ float red16_add(float x) {
    x += dpp_mov<0xB1>(x);     // quad_perm xor1
    x += dpp_mov<0x4E>(x);     // quad_perm xor2
    x += dpp_mov<0x141>(x);    // row_half_mirror
    x += dpp_mov<0x140>(x);    // row_mirror
    return x;
}

// ---------------------------------------------------------------------------
__global__ __launch_bounds__(256) void convert_flat(
    const float* __restrict__ src, unsigned short* __restrict__ dst)
{
    const int i = blockIdx.x * 256 + threadIdx.x;
    const float4 v = ((const float4*)src)[i];
    ushort4 o;
    o.x = f2b(v.x); o.y = f2b(v.y); o.z = f2b(v.z); o.w = f2b(v.w);
    ((ushort4*)dst)[i] = o;
}

struct WPack { const float* s[6]; unsigned short* d[6]; };
__global__ __launch_bounds__(256) void convert_w(WPack p)
{
    const int mat = blockIdx.x >> 8;
    const int k = blockIdx.x & 255;
    const int c = threadIdx.x;
    p.d[mat][(size_t)c * DD + k] = f2b(p.s[mat][(size_t)k * DD + c]);
}

template<int SEQ>
__global__ __launch_bounds__(256) void transpose_v(
    const unsigned short* __restrict__ Xb, unsigned short* __restrict__ VT)
{
    const int m = blockIdx.x * 256 + threadIdx.x;
    const int c0 = blockIdx.y * 8;
    const int b = blockIdx.z;
    const bf16x8 v = *(const bf16x8*)&Xb[((size_t)b * SEQ + m) * DD + c0];
    #pragma unroll
    for (int j = 0; j < 8; ++j)
        VT[((size_t)b * DD + c0 + j) * SEQ + m] = (unsigned short)v[j];
}

// ---------------------------------------------------------------------------
// bf16 MFMA GEMM: C[R,256] = A[R,256] @ W  (Wt pre-transposed)
// ---------------------------------------------------------------------------
template<bool OUTPROJ>
__global__ __launch_bounds__(256) void gemm_bf16(
    const unsigned short* __restrict__ A,
    const unsigned short* __restrict__ Wt,
    float outscale,
    const float* __restrict__ bias,
    const float* __restrict__ feats,
    unsigned short* __restrict__ Cb,
    float* __restrict__ Cf)
{
    __shared__ unsigned short As[64][72];
    __shared__ unsigned short Ws[64][72];
    const int tid = threadIdx.x;
    const int lane = tid & 63, w = tid >> 6;
    const int r0 = blockIdx.x * 64, c0 = blockIdx.y * 64;
    const int rq = (w >> 1) * 32, cq = (w & 1) * 32;
    const int srow = tid >> 2, skc = (tid & 3) * 16;
    const int g = lane >> 4, cl = lane & 15;

    f32x4 acc[2][2] = {};

    for (int ks = 0; ks < DD; ks += 64) {
        __syncthreads();
        {
            const unsigned short* ga = &A[(size_t)(r0 + srow) * DD + ks + skc];
            *(bf16x8*)&As[srow][skc]     = *(const bf16x8*)ga;
            *(bf16x8*)&As[srow][skc + 8] = *(const bf16x8*)(ga + 8);
            const unsigned short* gw = &Wt[(size_t)(c0 + srow) * DD + ks + skc];
            *(bf16x8*)&Ws[srow][skc]     = *(const bf16x8*)gw;
            *(bf16x8*)&Ws[srow][skc + 8] = *(const bf16x8*)(gw + 8);
        }
        __syncthreads();
        #pragma unroll
        for (int kh = 0; kh < 2; ++kh) {
            const int kk = kh * 32 + g * 8;
            const bf16x8 a0 = *(const bf16x8*)&As[rq + cl][kk];
            const bf16x8 a1 = *(const bf16x8*)&As[rq + 16 + cl][kk];
            const bf16x8 b0 = *(const bf16x8*)&Ws[cq + cl][kk];
            const bf16x8 b1 = *(const bf16x8*)&Ws[cq + 16 + cl][kk];
            acc[0][0] = __builtin_amdgcn_mfma_f32_16x16x32_bf16(a0, b0, acc[0][0], 0, 0, 0);
            acc[0][1] = __builtin_amdgcn_mfma_f32_16x16x32_bf16(a0, b1, acc[0][1], 0, 0, 0);
            acc[1][0] = __builtin_amdgcn_mfma_f32_16x16x32_bf16(a1, b0, acc[1][0], 0, 0, 0);
            acc[1][1] = __builtin_amdgcn_mfma_f32_16x16x32_bf16(a1, b1, acc[1][1], 0, 0, 0);
        }
    }

    #pragma unroll
    for (int sr = 0; sr < 2; ++sr)
    #pragma unroll
    for (int sc = 0; sc < 2; ++sc) {
        const int col = c0 + cq + sc * 16 + cl;
        #pragma unroll
        for (int reg = 0; reg < 4; ++reg) {
            const int row = r0 + rq + sr * 16 + g * 4 + reg;
            const size_t idx = (size_t)row * DD + col;
            if (OUTPROJ) {
                Cf[idx] = (acc[sr][sc][reg] + bias[col]) * feats[idx];
            } else {
                Cb[idx] = f2b(acc[sr][sc][reg] * outscale);
            }
        }
    }
}

// ---------------------------------------------------------------------------
// Attention body v3: 32 queries/wave (2 q-groups sharing K,V frags),
// K prefetched one tile ahead, V hoisted before the exp phase,
// no-max exp2 softmax (scores bounded; overflow-safe in f32).
// ---------------------------------------------------------------------------
template<int SEQK, int SPLIT, bool HAS_MASK>
__device__ __forceinline__ void attn_body(
    int bid,
    const unsigned short* __restrict__ Qb,
    const unsigned short* __restrict__ Kb,
    const unsigned short* __restrict__ VTb,
    const int* __restrict__ mask,
    unsigned short* __restrict__ ctx,
    float* __restrict__ Pl, unsigned short* __restrict__ PaccB,
    int NQ,
    unsigned short (*Pw)[32][88], float* maskadd)
{
    constexpr int KCHUNK = SEQK / SPLIT;
    constexpr int NT = KCHUNK / 64;

    const int tid = threadIdx.x;
    const int lane = tid & 63, w = tid >> 6;
    const int g = lane >> 4, cl = lane & 15;

    const int nqt = NQ / 128;
    int bi = bid;
    const int sp = bi % SPLIT; bi /= SPLIT;
    const int qt = bi % nqt;   bi /= nqt;
    const int h  = bi % HH;
    const int b  = bi / HH;
    const int q0 = qt * 128 + w * 32;
    const int kv0 = sp * KCHUNK;

    if (HAS_MASK) {
        for (int i = tid; i < SEQK; i += 256)
            maskadd[i] = mask[b * SEQK + i] ? -1e30f : 0.f;
        __syncthreads();
    }

    bf16x8 aq[2];
    aq[0] = *(const bf16x8*)&Qb[((size_t)b * NQ + q0 + cl) * DD + h * HDD + g * 8];
    aq[1] = *(const bf16x8*)&Qb[((size_t)b * NQ + q0 + 16 + cl) * DD + h * HDD + g * 8];
    const unsigned short* Kbase = &Kb[(size_t)b * SEQK * DD + h * HDD + g * 8];
    const unsigned short* Vbase = &VTb[((size_t)b * DD + h * HDD) * SEQK];

    float lsum[2][4] = {};
    f32x4 acc[2][2] = {};   // [qg][sub]

    bf16x8 Kc[4], Kn[4];
    #pragma unroll
    for (int kf = 0; kf < 4; ++kf)
        Kc[kf] = *(const bf16x8*)&Kbase[(size_t)(kv0 + kf * 16 + cl) * DD];

    for (int t = 0; t < NT; ++t) {
        const int m0 = kv0 + t * 64;

        // prefetch next K tile's B-frags (hidden under this tile's compute)
        if (t + 1 < NT) {
            #pragma unroll
            for (int kf = 0; kf < 4; ++kf)
                Kn[kf] = *(const bf16x8*)&Kbase[(size_t)(m0 + 64 + kf * 16 + cl) * DD];
        }

        // QK^T: S[32q][64key] in 8 D-frags
        f32x4 s[2][4];
        #pragma unroll
        for (int kf = 0; kf < 4; ++kf) {
            const f32x4 z = {0.f, 0.f, 0.f, 0.f};
            s[0][kf] = __builtin_amdgcn_mfma_f32_16x16x32_bf16(aq[0], Kc[kf], z, 0, 0, 0);
            s[1][kf] = __builtin_amdgcn_mfma_f32_16x16x32_bf16(aq[1], Kc[kf], z, 0, 0, 0);
        }

        // V frags issued early (hidden under exp + P-write phase)
        bf16x8 vv[2][2];
        #pragma unroll
        for (int mh = 0; mh < 2; ++mh)
            #pragma unroll
            for (int sub = 0; sub < 2; ++sub)
                vv[mh][sub] = *(const bf16x8*)
                    &Vbase[(size_t)(sub * 16 + cl) * SEQK + m0 + mh * 32 + g * 8];

        // P = exp2(s [+mask]); per-lane l; P -> wave-private LDS (bf16)
        #pragma unroll
        for (int kf = 0; kf < 4; ++kf) {
            const float madd = HAS_MASK ? maskadd[m0 + kf * 16 + cl] : 0.f;
            #pragma unroll
            for (int qg = 0; qg < 2; ++qg)
                #pragma unroll
                for (int reg = 0; reg < 4; ++reg) {
                    const float p = exp2f(s[qg][kf][reg] + madd);
                    lsum[qg][reg] += p;
                    Pw[w][qg * 16 + g * 4 + reg][kf * 16 + cl] = f2b(p);
                }
        }

        // PV: acc[32q][32c] += P[32q][64m] x V[64m][32c]
        #pragma unroll
        for (int mh = 0; mh < 2; ++mh) {
            const bf16x8 pa0 = *(const bf16x8*)&Pw[w][cl][mh * 32 + g * 8];
            const bf16x8 pa1 = *(const bf16x8*)&Pw[w][16 + cl][mh * 32 + g * 8];
            #pragma unroll
            for (int sub = 0; sub < 2; ++sub) {
                acc[0][sub] = __builtin_amdgcn_mfma_f32_16x16x32_bf16(pa0, vv[mh][sub], acc[0][sub], 0, 0, 0);
                acc[1][sub] = __builtin_amdgcn_mfma_f32_16x16x32_bf16(pa1, vv[mh][sub], acc[1][sub], 0, 0, 0);
            }
        }

        #pragma unroll
        for (int kf = 0; kf < 4; ++kf) Kc[kf] = Kn[kf];
    }

    // row-sum reduce over 16 key-lanes (once per kernel)
    #pragma unroll
    for (int qg = 0; qg < 2; ++qg)
        #pragma unroll
        for (int reg = 0; reg < 4; ++reg)
            lsum[qg][reg] = red16_add(lsum[qg][reg]);

    if (SPLIT > 1) {
        const int pb = bid;
        #pragma unroll
        for (int qg = 0; qg < 2; ++qg) {
            #pragma unroll
            for (int sub = 0; sub < 2; ++sub)
                #pragma unroll
                for (int reg = 0; reg < 4; ++reg) {
                    const int wq = w * 32 + qg * 16 + g * 4 + reg;
                    PaccB[((size_t)pb * 128 + wq) * 32 + sub * 16 + cl]
                        = f2b(acc[qg][sub][reg]);
                }
            if (cl == 0) {
                #pragma unroll
                for (int reg = 0; reg < 4; ++reg)
                    Pl[(size_t)pb * 128 + w * 32 + qg * 16 + g * 4 + reg]
                        = lsum[qg][reg];
            }
        }
    } else {
        #pragma unroll
        for (int qg = 0; qg < 2; ++qg)
            #pragma unroll
            for (int sub = 0; sub < 2; ++sub)
                #pragma unroll
                for (int reg = 0; reg < 4; ++reg) {
                    const int q = q0 + qg * 16 + g * 4 + reg;
                    ctx[((size_t)b * NQ + q) * DD + h * HDD + sub * 16 + cl]
                        = f2b(acc[qg][sub][reg] / lsum[qg][reg]);
                }
    }
}

// ---------------------------------------------------------------------------
// Fused: dir A (blocks 0..1023, SPLIT=8) + dir B (1024..2047), uniform NT=8.
// ---------------------------------------------------------------------------
__global__ __launch_bounds__(256) void attn_fused(
    const unsigned short* __restrict__ amr_qk,
    const unsigned short* __restrict__ vis_qk,
    const unsigned short* __restrict__ VT_vis,
    const unsigned short* __restrict__ VT_amr,
    const int* __restrict__ mask,
    unsigned short* __restrict__ ctx1,
    float* __restrict__ Pl, unsigned short* __restrict__ PaccB)
{
    __shared__ unsigned short Pw[4][32][88];
    __shared__ float maskadd[NN];
    constexpr int NA = (NN / 128) * HH * BB * 8;   // 1024 dir-A blocks
    if (blockIdx.x < NA) {
        attn_body<MM, 8, false>(blockIdx.x, amr_qk, vis_qk, VT_vis, nullptr,
                                nullptr, Pl, PaccB, NN, Pw, maskadd);
    } else {
        attn_body<NN, 1, true>(blockIdx.x - NA, vis_qk, amr_qk, VT_amr, mask,
                               ctx1, nullptr, nullptr, MM, Pw, maskadd);
    }
}

// ---------------------------------------------------------------------------
// Combine 8 split partials (bf16 acc, f32 l): out = sum(acc)/sum(l)
// grid = 128 blocks (one per (b,h,qt)), 256 threads.
// ---------------------------------------------------------------------------
__global__ __launch_bounds__(256) void combine_split(
    const float* __restrict__ Pl, const unsigned short* __restrict__ PaccB,
    unsigned short* __restrict__ ctx)
{
    const int tid = threadIdx.x;
    const int q = tid >> 1, ch = tid & 1;
    const int bqt = blockIdx.x;
    const int qt = bqt & 3, h = (bqt >> 2) & 7, b = bqt >> 5;
    const int pb0 = bqt * 8;

    float denom = 0.f;
    float o[16] = {};
    #pragma unroll
    for (int sp = 0; sp < 8; ++sp) {
        const size_t base = ((size_t)(pb0 + sp) * 128 + q) * 32 + ch * 16;
        const bf16x8 a0 = *(const bf16x8*)&PaccB[base];
        const bf16x8 a1 = *(const bf16x8*)&PaccB[base + 8];
        #pragma unroll
        for (int j = 0; j < 8; ++j) {
            o[j]     += b2f((unsigned short)a0[j]);
            o[8 + j] += b2f((unsigned short)a1[j]);
        }
        denom += Pl[(size_t)(pb0 + sp) * 128 + q];
    }
    const float inv = 1.f / denom;

    unsigned short* dst = &ctx[((size_t)b * NN + qt * 128 + q) * DD + h * HDD + ch * 16];
    ushort4 u;
    #pragma unroll
    for (int j4 = 0; j4 < 4; ++j4) {
        u.x = f2b(o[j4 * 4 + 0] * inv); u.y = f2b(o[j4 * 4 + 1] * inv);
        u.z = f2b(o[j4 * 4 + 2] * inv); u.w = f2b(o[j4 * 4 + 3] * inv);
        *(ushort4*)(dst + j4 * 4) = u;
    }
}

// ---------------------------------------------------------------------------
extern "C" void kernel_launch(void* const* d_in, const int* in_sizes, int n_in,
                              void* d_out, int out_size, void* d_ws, size_t ws_size,
                              hipStream_t stream)
{
    const float* amr_feats    = (const float*)d_in[0];
    const int*   amr_pad_mask = (const int*)d_in[1];
    const float* visual_feats = (const float*)d_in[2];
    const float* W_amr_qk     = (const float*)d_in[3];
    const float* W_amr_v      = (const float*)d_in[4];
    const float* W_vis_qk     = (const float*)d_in[5];
    const float* W_vis_v      = (const float*)d_in[6];
    const float* W_amr_out    = (const float*)d_in[7];
    const float* b_amr_out    = (const float*)d_in[8];
    const float* W_vis_out    = (const float*)d_in[9];
    const float* b_vis_out    = (const float*)d_in[10];

    // bf16 workspace (u16 offsets), total 48.0 MB
    unsigned short* ws = (unsigned short*)d_ws;
    unsigned short* amr_fb     = ws;                    // dead after GEMM 1-2
    unsigned short* vis_fb     = ws + 524288;           // dead after GEMM 3-4
    unsigned short* Wt_amr_qk  = ws + 4718592;
    unsigned short* Wt_amr_v   = ws + 4784128;
    unsigned short* Wt_vis_qk  = ws + 4849664;
    unsigned short* Wt_vis_v   = ws + 4915200;
    unsigned short* Wt_amr_out = ws + 4980736;
    unsigned short* Wt_vis_out = ws + 5046272;
    unsigned short* amr_qk_b   = ws + 5111808;
    unsigned short* amr_v_b    = ws + 5636096;
    unsigned short* vis_qk_b   = ws + 6160384;
    unsigned short* vis_v_b    = ws + 10354688;
    unsigned short* ctx0_b     = ws + 14548992;
    unsigned short* ctx1_b     = ws + 15073280;
    unsigned short* VT_vis     = ws + 19267584;
    unsigned short* VT_amr     = ws + 23461888;
    // split partials alias the dead amr_fb/vis_fb region:
    // Pl f32 [1024*128] = 0..262144 u16; PaccB bf16 [1024*128*32] = 262144..4456448 u16
    float* Pl            = (float*)ws;
    unsigned short* PaccB = ws + 262144;

    float* out0 = (float*)d_out;
    float* out1 = out0 + (size_t)BB * NN * DD;

    // sqrt( HD^-0.5 * log2(e) ) folded into BOTH qk projections -> exp2 domain
    const float SQS = 0.50500976f;

    // 0) conversions
    convert_flat<<<512, 256, 0, stream>>>(amr_feats, amr_fb);
    convert_flat<<<4096, 256, 0, stream>>>(visual_feats, vis_fb);
    WPack wp;
    wp.s[0] = W_amr_qk;  wp.d[0] = Wt_amr_qk;
    wp.s[1] = W_amr_v;   wp.d[1] = Wt_amr_v;
    wp.s[2] = W_vis_qk;  wp.d[2] = Wt_vis_qk;
    wp.s[3] = W_vis_v;   wp.d[3] = Wt_vis_v;
    wp.s[4] = W_amr_out; wp.d[4] = Wt_amr_out;
    wp.s[5] = W_vis_out; wp.d[5] = Wt_vis_out;
    convert_w<<<1536, 256, 0, stream>>>(wp);

    // 1) input projections
    gemm_bf16<false><<<dim3(32, 4), 256, 0, stream>>>(
        amr_fb, Wt_amr_qk, SQS, nullptr, nullptr, amr_qk_b, nullptr);
    gemm_bf16<false><<<dim3(32, 4), 256, 0, stream>>>(
        amr_fb, Wt_amr_v, 1.f, nullptr, nullptr, amr_v_b, nullptr);
    gemm_bf16<false><<<dim3(256, 4), 256, 0, stream>>>(
        vis_fb, Wt_vis_qk, SQS, nullptr, nullptr, vis_qk_b, nullptr);
    gemm_bf16<false><<<dim3(256, 4), 256, 0, stream>>>(
        vis_fb, Wt_vis_v, 1.f, nullptr, nullptr, vis_v_b, nullptr);

    // 1b) V transposes for the PV B-operand
    transpose_v<MM><<<dim3(16, 32, 4), 256, 0, stream>>>(vis_v_b, VT_vis);
    transpose_v<NN><<<dim3(2, 32, 4), 256, 0, stream>>>(amr_v_b, VT_amr);

    // 2) both attention directions in ONE launch (uniform 8-tile blocks)
    attn_fused<<<2048, 256, 0, stream>>>(
        amr_qk_b, vis_qk_b, VT_vis, VT_amr, amr_pad_mask, ctx1_b, Pl, PaccB);
    combine_split<<<128, 256, 0, stream>>>(Pl, PaccB, ctx0_b);

    // 3) output projections + bias + elementwise multiply (f32 out)
    gemm_bf16<true><<<dim3(32, 4), 256, 0, stream>>>(
        ctx0_b, Wt_amr_out, 1.f, b_amr_out, amr_feats, nullptr, out0);
    gemm_bf16<true><<<dim3(256, 4), 256, 0, stream>>>(
        ctx1_b, Wt_vis_out, 1.f, b_vis_out, visual_feats, nullptr, out1);
}

// Round 8
// 116.620 us; speedup vs baseline: 24.8866x; 1.1432x over previous
//
#include <hip/hip_runtime.h>

#define BB 4
#define NN 512
#define MM 4096
#define DD 256
#define HH 8
#define HDD 32

typedef __attribute__((ext_vector_type(8))) short bf16x8;
typedef __attribute__((ext_vector_type(4))) float f32x4;

__device__ __forceinline__ unsigned short f2b(float f) {
    union { float f; unsigned u; } v; v.f = f;
    unsigned r = v.u + 0x7fffu + ((v.u >> 16) & 1u);
    return (unsigned short)(r >> 16);
}
__device__ __forceinline__ float b2f(unsigned short u) {
    union { unsigned u; float f; } v; v.u = ((unsigned)u) << 16;
    return v.f;
}
// packed f32x2 -> bf16x2 (RNE), gfx950 has the instruction but no builtin
__device__ __forceinline__ unsigned cvt_pk_bf16(float lo, float hi) {
    unsigned r;
    asm("v_cvt_pk_bf16_f32 %0, %1, %2" : "=v"(r) : "v"(lo), "v"(hi));
    return r;
}

// ---------------------------------------------------------------------------
// feats f32 -> bf16 (both tensors, one launch)
// ---------------------------------------------------------------------------
__global__ __launch_bounds__(256) void convert_feats(
    const float* __restrict__ amr, const float* __restrict__ vis,
    unsigned short* __restrict__ da, unsigned short* __restrict__ dv)
{
    const int bx = blockIdx.x;
    const float* s; unsigned short* d; int i;
    if (bx < 512) { s = amr; d = da; i = bx * 256 + threadIdx.x; }
    else          { s = vis; d = dv; i = (bx - 512) * 256 + threadIdx.x; }
    const float4 v = ((const float4*)s)[i];
    ushort4 o;
    o.x = f2b(v.x); o.y = f2b(v.y); o.z = f2b(v.z); o.w = f2b(v.w);
    ((ushort4*)d)[i] = o;
}

struct WPack { const float* s[6]; unsigned short* d[6]; };
__global__ __launch_bounds__(256) void convert_w(WPack p)
{
    const int mat = blockIdx.x >> 8;
    const int k = blockIdx.x & 255;
    const int c = threadIdx.x;
    p.d[mat][(size_t)c * DD + k] = f2b(p.s[mat][(size_t)k * DD + c]);
}

// V transposes, both tensors in one launch. grid (18, 32, 4)
__global__ __launch_bounds__(256) void transpose_all(
    const unsigned short* __restrict__ visV,
    const unsigned short* __restrict__ amrV,
    unsigned short* __restrict__ VTv, unsigned short* __restrict__ VTa)
{
    const int bx = blockIdx.x;
    const unsigned short* X; unsigned short* VT; int SEQ, mb;
    if (bx < 16) { X = visV; VT = VTv; SEQ = MM; mb = bx; }
    else         { X = amrV; VT = VTa; SEQ = NN; mb = bx - 16; }
    const int m = mb * 256 + threadIdx.x;
    const int c0 = blockIdx.y * 8;
    const int b = blockIdx.z;
    const bf16x8 v = *(const bf16x8*)&X[((size_t)b * SEQ + m) * DD + c0];
    #pragma unroll
    for (int j = 0; j < 8; ++j)
        VT[((size_t)b * DD + c0 + j) * SEQ + m] = (unsigned short)v[j];
}

// ---------------------------------------------------------------------------
// Shared 64x64 MFMA GEMM tile body (K=256)
// ---------------------------------------------------------------------------
template<bool OUTPROJ>
__device__ __forceinline__ void gemm_tile(
    const unsigned short* __restrict__ A,
    const unsigned short* __restrict__ Wt,
    float outscale,
    const float* __restrict__ bias,
    const float* __restrict__ feats,
    unsigned short* __restrict__ Cb,
    float* __restrict__ Cf,
    int r0, int c0,
    unsigned short (*As)[72], unsigned short (*Ws)[72])
{
    const int tid = threadIdx.x;
    const int lane = tid & 63, w = tid >> 6;
    const int rq = (w >> 1) * 32, cq = (w & 1) * 32;
    const int srow = tid >> 2, skc = (tid & 3) * 16;
    const int g = lane >> 4, cl = lane & 15;

    f32x4 acc[2][2] = {};

    for (int ks = 0; ks < DD; ks += 64) {
        __syncthreads();
        {
            const unsigned short* ga = &A[(size_t)(r0 + srow) * DD + ks + skc];
            *(bf16x8*)&As[srow][skc]     = *(const bf16x8*)ga;
            *(bf16x8*)&As[srow][skc + 8] = *(const bf16x8*)(ga + 8);
            const unsigned short* gw = &Wt[(size_t)(c0 + srow) * DD + ks + skc];
            *(bf16x8*)&Ws[srow][skc]     = *(const bf16x8*)gw;
            *(bf16x8*)&Ws[srow][skc + 8] = *(const bf16x8*)(gw + 8);
        }
        __syncthreads();
        #pragma unroll
        for (int kh = 0; kh < 2; ++kh) {
            const int kk = kh * 32 + g * 8;
            const bf16x8 a0 = *(const bf16x8*)&As[rq + cl][kk];
            const bf16x8 a1 = *(const bf16x8*)&As[rq + 16 + cl][kk];
            const bf16x8 b0 = *(const bf16x8*)&Ws[cq + cl][kk];
            const bf16x8 b1 = *(const bf16x8*)&Ws[cq + 16 + cl][kk];
            acc[0][0] = __builtin_amdgcn_mfma_f32_16x16x32_bf16(a0, b0, acc[0][0], 0, 0, 0);
            acc[0][1] = __builtin_amdgcn_mfma_f32_16x16x32_bf16(a0, b1, acc[0][1], 0, 0, 0);
            acc[1][0] = __builtin_amdgcn_mfma_f32_16x16x32_bf16(a1, b0, acc[1][0], 0, 0, 0);
            acc[1][1] = __builtin_amdgcn_mfma_f32_16x16x32_bf16(a1, b1, acc[1][1], 0, 0, 0);
        }
    }

    #pragma unroll
    for (int sr = 0; sr < 2; ++sr)
    #pragma unroll
    for (int sc = 0; sc < 2; ++sc) {
        const int col = c0 + cq + sc * 16 + cl;
        #pragma unroll
        for (int reg = 0; reg < 4; ++reg) {
            const int row = r0 + rq + sr * 16 + g * 4 + reg;
            const size_t idx = (size_t)row * DD + col;
            if (OUTPROJ) {
                Cf[idx] = (acc[sr][sc][reg] + bias[col]) * feats[idx];
            } else {
                Cb[idx] = f2b(acc[sr][sc][reg] * outscale);
            }
        }
    }
}

// All 4 input projections in one launch. x-blocks: 32 amr_qk | 32 amr_v |
// 256 vis_qk | 256 vis_v  (576 total), y = col-tile (4).
struct InPack {
    const unsigned short* A[4];
    const unsigned short* Wt[4];
    unsigned short* C[4];
    float scale[4];
};
__global__ __launch_bounds__(256) void gemm_in(InPack p)
{
    __shared__ unsigned short As[64][72];
    __shared__ unsigned short Ws[64][72];
    const int bx = blockIdx.x;
    int which, rb;
    if (bx < 32)       { which = 0; rb = bx; }
    else if (bx < 64)  { which = 1; rb = bx - 32; }
    else if (bx < 320) { which = 2; rb = bx - 64; }
    else               { which = 3; rb = bx - 320; }
    gemm_tile<false>(p.A[which], p.Wt[which], p.scale[which], nullptr, nullptr,
                     p.C[which], nullptr, rb * 64, blockIdx.y * 64, As, Ws);
}

// Both output projections in one launch. x: 32 amr | 256 vis (288), y = 4.
struct OutPack {
    const unsigned short* A[2];
    const unsigned short* Wt[2];
    const float* bias[2];
    const float* feats[2];
    float* O[2];
};
__global__ __launch_bounds__(256) void gemm_out(OutPack p)
{
    __shared__ unsigned short As[64][72];
    __shared__ unsigned short Ws[64][72];
    const int bx = blockIdx.x;
    const int which = (bx < 32) ? 0 : 1;
    const int rb = (bx < 32) ? bx : bx - 32;
    gemm_tile<true>(p.A[which], p.Wt[which], 1.f, p.bias[which], p.feats[which],
                    nullptr, p.O[which], rb * 64, blockIdx.y * 64, As, Ws);
}

// ---------------------------------------------------------------------------
// Attention body v4: swapped QK^T (S^T layout -> key-adjacent P per lane),
// cvt_pk_bf16 packing, ds_write_b64 P stores, scalar lsum per lane.
// 32 q/wave, K prefetch 1 tile ahead, V hoisted, no-max exp2 softmax.
// ---------------------------------------------------------------------------
template<int SEQK, int SPLIT, bool HAS_MASK>
__device__ __forceinline__ void attn_body(
    int bid,
    const unsigned short* __restrict__ Qb,
    const unsigned short* __restrict__ Kb,
    const unsigned short* __restrict__ VTb,
    const int* __restrict__ mask,
    unsigned short* __restrict__ ctx,
    float* __restrict__ Pl, unsigned short* __restrict__ PaccB,
    int NQ,
    unsigned short (*Pw)[32][72], float* maskadd)
{
    constexpr int KCHUNK = SEQK / SPLIT;
    constexpr int NT = KCHUNK / 64;

    const int tid = threadIdx.x;
    const int lane = tid & 63, w = tid >> 6;
    const int g = lane >> 4, cl = lane & 15;

    const int nqt = NQ / 128;
    int bi = bid;
    const int sp = bi % SPLIT; bi /= SPLIT;
    const int qt = bi % nqt;   bi /= nqt;
    const int h  = bi % HH;
    const int b  = bi / HH;
    const int q0 = qt * 128 + w * 32;
    const int kv0 = sp * KCHUNK;

    if (HAS_MASK) {
        for (int i = tid; i < SEQK; i += 256)
            maskadd[i] = mask[b * SEQK + i] ? -1e30f : 0.f;
        __syncthreads();
    }

    bf16x8 aq[2];
    aq[0] = *(const bf16x8*)&Qb[((size_t)b * NQ + q0 + cl) * DD + h * HDD + g * 8];
    aq[1] = *(const bf16x8*)&Qb[((size_t)b * NQ + q0 + 16 + cl) * DD + h * HDD + g * 8];
    const unsigned short* Kbase = &Kb[(size_t)b * SEQK * DD + h * HDD + g * 8];
    const unsigned short* Vbase = &VTb[((size_t)b * DD + h * HDD) * SEQK];

    float lsum[2] = {0.f, 0.f};
    f32x4 acc[2][2] = {};   // [qg][sub]

    bf16x8 Kc[4], Kn[4];
    #pragma unroll
    for (int kf = 0; kf < 4; ++kf)
        Kc[kf] = *(const bf16x8*)&Kbase[(size_t)(kv0 + kf * 16 + cl) * DD];

    for (int t = 0; t < NT; ++t) {
        const int m0 = kv0 + t * 64;

        // prefetch next K tile's frags (hidden under this tile's compute)
        if (t + 1 < NT) {
            #pragma unroll
            for (int kf = 0; kf < 4; ++kf)
                Kn[kf] = *(const bf16x8*)&Kbase[(size_t)(m0 + 64 + kf * 16 + cl) * DD];
        }

        // swapped QK^T: S^T frags; lane holds q=cl, keys kf*16+g*4+reg
        f32x4 s[2][4];
        #pragma unroll
        for (int kf = 0; kf < 4; ++kf) {
            const f32x4 z = {0.f, 0.f, 0.f, 0.f};
            s[0][kf] = __builtin_amdgcn_mfma_f32_16x16x32_bf16(Kc[kf], aq[0], z, 0, 0, 0);
            s[1][kf] = __builtin_amdgcn_mfma_f32_16x16x32_bf16(Kc[kf], aq[1], z, 0, 0, 0);
        }

        // V frags issued early (hidden under exp + P-write phase)
        bf16x8 vv[2][2];
        #pragma unroll
        for (int mh = 0; mh < 2; ++mh)
            #pragma unroll
            for (int sub = 0; sub < 2; ++sub)
                vv[mh][sub] = *(const bf16x8*)
                    &Vbase[(size_t)(sub * 16 + cl) * SEQK + m0 + mh * 32 + g * 8];

        // P = exp2(s [+mask]); pack pairs; b64 stores to Pw[q][key]
        #pragma unroll
        for (int kf = 0; kf < 4; ++kf) {
            f32x4 madd;
            if (HAS_MASK)
                madd = *(const f32x4*)&maskadd[m0 + kf * 16 + g * 4];
            #pragma unroll
            for (int qg = 0; qg < 2; ++qg) {
                const float p0 = exp2f(s[qg][kf][0] + (HAS_MASK ? madd[0] : 0.f));
                const float p1 = exp2f(s[qg][kf][1] + (HAS_MASK ? madd[1] : 0.f));
                const float p2 = exp2f(s[qg][kf][2] + (HAS_MASK ? madd[2] : 0.f));
                const float p3 = exp2f(s[qg][kf][3] + (HAS_MASK ? madd[3] : 0.f));
                lsum[qg] += (p0 + p1) + (p2 + p3);
                uint2 u;
                u.x = cvt_pk_bf16(p0, p1);
                u.y = cvt_pk_bf16(p2, p3);
                *(uint2*)&Pw[w][qg * 16 + cl][kf * 16 + g * 4] = u;
            }
        }

        // PV: acc[32q][32c] += P[32q][64m] x V[64m][32c]
        #pragma unroll
        for (int mh = 0; mh < 2; ++mh) {
            const bf16x8 pa0 = *(const bf16x8*)&Pw[w][cl][mh * 32 + g * 8];
            const bf16x8 pa1 = *(const bf16x8*)&Pw[w][16 + cl][mh * 32 + g * 8];
            #pragma unroll
            for (int sub = 0; sub < 2; ++sub) {
                acc[0][sub] = __builtin_amdgcn_mfma_f32_16x16x32_bf16(pa0, vv[mh][sub], acc[0][sub], 0, 0, 0);
                acc[1][sub] = __builtin_amdgcn_mfma_f32_16x16x32_bf16(pa1, vv[mh][sub], acc[1][sub], 0, 0, 0);
            }
        }

        #pragma unroll
        for (int kf = 0; kf < 4; ++kf) Kc[kf] = Kn[kf];
    }

    // total l per q=cl: reduce across the 4 g-groups (lanes cl, cl+16, +32, +48)
    #pragma unroll
    for (int qg = 0; qg < 2; ++qg) {
        lsum[qg] += __shfl_xor(lsum[qg], 16);
        lsum[qg] += __shfl_xor(lsum[qg], 32);
    }

    if (SPLIT > 1) {
        const int pb = bid;
        #pragma unroll
        for (int qg = 0; qg < 2; ++qg) {
            #pragma unroll
            for (int sub = 0; sub < 2; ++sub)
                #pragma unroll
                for (int reg = 0; reg < 4; ++reg) {
                    const int wq = w * 32 + qg * 16 + g * 4 + reg;
                    PaccB[((size_t)pb * 128 + wq) * 32 + sub * 16 + cl]
                        = f2b(acc[qg][sub][reg]);
                }
            if (g == 0)
                Pl[(size_t)pb * 128 + w * 32 + qg * 16 + cl] = lsum[qg];
        }
    } else {
        // redistribute l: acc rows are q = g*4+reg; lsum lives at lane cl=q
        float linv[2][4];
        #pragma unroll
        for (int qg = 0; qg < 2; ++qg)
            #pragma unroll
            for (int reg = 0; reg < 4; ++reg)
                linv[qg][reg] = __shfl(lsum[qg], g * 4 + reg);
        #pragma unroll
        for (int qg = 0; qg < 2; ++qg)
            #pragma unroll
            for (int sub = 0; sub < 2; ++sub)
                #pragma unroll
                for (int reg = 0; reg < 4; ++reg) {
                    const int q = q0 + qg * 16 + g * 4 + reg;
                    ctx[((size_t)b * NQ + q) * DD + h * HDD + sub * 16 + cl]
                        = f2b(acc[qg][sub][reg] / linv[qg][reg]);
                }
    }
}

// Fused: dir A (blocks 0..1023, SPLIT=8) + dir B (1024..2047), uniform NT=8.
__global__ __launch_bounds__(256) void attn_fused(
    const unsigned short* __restrict__ amr_qk,
    const unsigned short* __restrict__ vis_qk,
    const unsigned short* __restrict__ VT_vis,
    const unsigned short* __restrict__ VT_amr,
    const int* __restrict__ mask,
    unsigned short* __restrict__ ctx1,
    float* __restrict__ Pl, unsigned short* __restrict__ PaccB)
{
    __shared__ unsigned short Pw[4][32][72];
    __shared__ float maskadd[NN];
    constexpr int NA = (NN / 128) * HH * BB * 8;   // 1024 dir-A blocks
    if (blockIdx.x < NA) {
        attn_body<MM, 8, false>(blockIdx.x, amr_qk, vis_qk, VT_vis, nullptr,
                                nullptr, Pl, PaccB, NN, Pw, maskadd);
    } else {
        attn_body<NN, 1, true>(blockIdx.x - NA, vis_qk, amr_qk, VT_amr, mask,
                               ctx1, nullptr, nullptr, MM, Pw, maskadd);
    }
}

// Combine 8 split partials (bf16 acc, f32 l): out = sum(acc)/sum(l)
__global__ __launch_bounds__(256) void combine_split(
    const float* __restrict__ Pl, const unsigned short* __restrict__ PaccB,
    unsigned short* __restrict__ ctx)
{
    const int tid = threadIdx.x;
    const int q = tid >> 1, ch = tid & 1;
    const int bqt = blockIdx.x;
    const int qt = bqt & 3, h = (bqt >> 2) & 7, b = bqt >> 5;
    const int pb0 = bqt * 8;

    float denom = 0.f;
    float o[16] = {};
    #pragma unroll
    for (int sp = 0; sp < 8; ++sp) {
        const size_t base = ((size_t)(pb0 + sp) * 128 + q) * 32 + ch * 16;
        const bf16x8 a0 = *(const bf16x8*)&PaccB[base];
        const bf16x8 a1 = *(const bf16x8*)&PaccB[base + 8];
        #pragma unroll
        for (int j = 0; j < 8; ++j) {
            o[j]     += b2f((unsigned short)a0[j]);
            o[8 + j] += b2f((unsigned short)a1[j]);
        }
        denom += Pl[(size_t)(pb0 + sp) * 128 + q];
    }
    const float inv = 1.f / denom;

    unsigned short* dst = &ctx[((size_t)b * NN + qt * 128 + q) * DD + h * HDD + ch * 16];
    ushort4 u;
    #pragma unroll
    for (int j4 = 0; j4 < 4; ++j4) {
        u.x = f2b(o[j4 * 4 + 0] * inv); u.y = f2b(o[j4 * 4 + 1] * inv);
        u.z = f2b(o[j4 * 4 + 2] * inv); u.w = f2b(o[j4 * 4 + 3] * inv);
        *(ushort4*)(dst + j4 * 4) = u;
    }
}

// ---------------------------------------------------------------------------
extern "C" void kernel_launch(void* const* d_in, const int* in_sizes, int n_in,
                              void* d_out, int out_size, void* d_ws, size_t ws_size,
                              hipStream_t stream)
{
    const float* amr_feats    = (const float*)d_in[0];
    const int*   amr_pad_mask = (const int*)d_in[1];
    const float* visual_feats = (const float*)d_in[2];
    const float* W_amr_qk     = (const float*)d_in[3];
    const float* W_amr_v      = (const float*)d_in[4];
    const float* W_vis_qk     = (const float*)d_in[5];
    const float* W_vis_v      = (const float*)d_in[6];
    const float* W_amr_out    = (const float*)d_in[7];
    const float* b_amr_out    = (const float*)d_in[8];
    const float* W_vis_out    = (const float*)d_in[9];
    const float* b_vis_out    = (const float*)d_in[10];

    // bf16 workspace (u16 offsets), total 48.0 MB
    unsigned short* ws = (unsigned short*)d_ws;
    unsigned short* amr_fb     = ws;                    // dead after gemm_in
    unsigned short* vis_fb     = ws + 524288;           // dead after gemm_in
    unsigned short* Wt_amr_qk  = ws + 4718592;
    unsigned short* Wt_amr_v   = ws + 4784128;
    unsigned short* Wt_vis_qk  = ws + 4849664;
    unsigned short* Wt_vis_v   = ws + 4915200;
    unsigned short* Wt_amr_out = ws + 4980736;
    unsigned short* Wt_vis_out = ws + 5046272;
    unsigned short* amr_qk_b   = ws + 5111808;
    unsigned short* amr_v_b    = ws + 5636096;
    unsigned short* vis_qk_b   = ws + 6160384;
    unsigned short* vis_v_b    = ws + 10354688;
    unsigned short* ctx0_b     = ws + 14548992;
    unsigned short* ctx1_b     = ws + 15073280;
    unsigned short* VT_vis     = ws + 19267584;
    unsigned short* VT_amr     = ws + 23461888;
    // split partials alias the dead amr_fb/vis_fb staging region
    float* Pl             = (float*)ws;          // 1024*128 f32
    unsigned short* PaccB = ws + 262144;         // 1024*128*32 bf16

    float* out0 = (float*)d_out;
    float* out1 = out0 + (size_t)BB * NN * DD;

    // sqrt( HD^-0.5 * log2(e) ) folded into BOTH qk projections -> exp2 domain
    const float SQS = 0.50500976f;

    // 0) conversions (2 launches)
    convert_feats<<<4608, 256, 0, stream>>>(amr_feats, visual_feats, amr_fb, vis_fb);
    WPack wp;
    wp.s[0] = W_amr_qk;  wp.d[0] = Wt_amr_qk;
    wp.s[1] = W_amr_v;   wp.d[1] = Wt_amr_v;
    wp.s[2] = W_vis_qk;  wp.d[2] = Wt_vis_qk;
    wp.s[3] = W_vis_v;   wp.d[3] = Wt_vis_v;
    wp.s[4] = W_amr_out; wp.d[4] = Wt_amr_out;
    wp.s[5] = W_vis_out; wp.d[5] = Wt_vis_out;
    convert_w<<<1536, 256, 0, stream>>>(wp);

    // 1) all 4 input projections, one launch
    InPack ip;
    ip.A[0] = amr_fb; ip.Wt[0] = Wt_amr_qk; ip.C[0] = amr_qk_b; ip.scale[0] = SQS;
    ip.A[1] = amr_fb; ip.Wt[1] = Wt_amr_v;  ip.C[1] = amr_v_b;  ip.scale[1] = 1.f;
    ip.A[2] = vis_fb; ip.Wt[2] = Wt_vis_qk; ip.C[2] = vis_qk_b; ip.scale[2] = SQS;
    ip.A[3] = vis_fb; ip.Wt[3] = Wt_vis_v;  ip.C[3] = vis_v_b;  ip.scale[3] = 1.f;
    gemm_in<<<dim3(576, 4), 256, 0, stream>>>(ip);

    // 1b) V transposes, one launch
    transpose_all<<<dim3(18, 32, 4), 256, 0, stream>>>(vis_v_b, amr_v_b, VT_vis, VT_amr);

    // 2) both attention directions in ONE launch (uniform 8-tile blocks)
    attn_fused<<<2048, 256, 0, stream>>>(
        amr_qk_b, vis_qk_b, VT_vis, VT_amr, amr_pad_mask, ctx1_b, Pl, PaccB);
    combine_split<<<128, 256, 0, stream>>>(Pl, PaccB, ctx0_b);

    // 3) both output projections, one launch
    OutPack op;
    op.A[0] = ctx0_b; op.Wt[0] = Wt_amr_out; op.bias[0] = b_amr_out;
    op.feats[0] = amr_feats;    op.O[0] = out0;
    op.A[1] = ctx1_b; op.Wt[1] = Wt_vis_out; op.bias[1] = b_vis_out;
    op.feats[1] = visual_feats; op.O[1] = out1;
    gemm_out<<<dim3(288, 4), 256, 0, stream>>>(op);
}